// Round 5
// baseline (1651.450 us; speedup 1.0000x reference)
//
#include <hip/hip_runtime.h>
#include <stdint.h>

#define LROWS 4240
#define ROW0 8
#define NVALID 4097

typedef float f32x4 __attribute__((ext_vector_type(4)));
typedef short bf16x8 __attribute__((ext_vector_type(8)));

__device__ __forceinline__ unsigned short f2bf(float f) {
  unsigned u = __float_as_uint(f);
  u += 0x7fffu + ((u >> 16) & 1u);
  return (unsigned short)(u >> 16);
}
__device__ __forceinline__ float bf2f(unsigned short h) {
  return __uint_as_float(((unsigned)h) << 16);
}
// OCP e4m3fn codec via exponent-shift trick (exact, incl. subnormals, RNE)
__device__ __forceinline__ uint8_t f2fp8(float f) {
  f = fminf(fmaxf(f, -448.f), 448.f);
  unsigned u = __float_as_uint(f * 0x1p-120f);
  unsigned s = (u >> 24) & 0x80u;
  u &= 0x7fffffffu;
  u += 0x7ffffu + ((u >> 20) & 1u);
  return (uint8_t)(s | (u >> 20));
}
__device__ __forceinline__ float fp82f(unsigned b) {
  return __uint_as_float(((b & 0x80u) << 24) | ((b & 0x7fu) << 20)) * 0x1p120f;
}

// decode 8 fp8 + BN + ReLU -> 8 bf16 packed in uint4 (zero if !valid)
__device__ __forceinline__ uint4 stage8(uint2 raw, const float* __restrict__ sc,
                                        const float* __restrict__ sh, int c0, bool valid) {
  unsigned short o[8];
#pragma unroll
  for (int j = 0; j < 8; ++j) {
    float f = 0.f;
    if (valid) {
      unsigned byte = ((j < 4 ? raw.x : raw.y) >> (8 * (j & 3))) & 0xffu;
      f = fmaxf(fp82f(byte) * sc[c0 + j] + sh[c0 + j], 0.f);
    }
    o[j] = f2bf(f);
  }
  return make_uint4((unsigned)o[0] | ((unsigned)o[1] << 16),
                    (unsigned)o[2] | ((unsigned)o[3] << 16),
                    (unsigned)o[4] | ((unsigned)o[5] << 16),
                    (unsigned)o[6] | ((unsigned)o[7] << 16));
}

// ---------------- weight prepack: per-(K-step, colgroup) 1KB fragment blobs ----
// K-chunk (64 ch) = two consecutive 16/8KB steps -> chunk-contiguous blobs.
__global__ void prepack_w2_kernel(const float* __restrict__ w2, uint8_t* __restrict__ wp) {
  int i = blockIdx.x * 256 + threadIdx.x;
  if (i >= 163840) return;
  int t = i % 5, oc = i / 5;
  int cin = oc & 127, o = oc >> 7;
  int step = t * 4 + (cin >> 5);
  int og = o >> 4;
  int lane = ((cin >> 3) & 3) * 16 + (o & 15);
  int j = cin & 7;
  *(unsigned short*)(wp + ((size_t)(step * 16 + og) << 10) + lane * 16 + j * 2) = f2bf(w2[i]);
}
__global__ void prepack_w3_kernel(const float* __restrict__ w3, uint8_t* __restrict__ wp) {
  int i = blockIdx.x * 256 + threadIdx.x;
  if (i >= 98304) return;
  int t = i % 3, oc = i / 3;
  int cin = oc & 255, o = oc >> 8;
  int step = t * 8 + (cin >> 5);
  int og = o >> 4;
  int lane = ((cin >> 3) & 3) * 16 + (o & 15);
  int j = cin & 7;
  *(unsigned short*)(wp + ((size_t)(step * 8 + og) << 10) + lane * 16 + j * 2) = f2bf(w3[i]);
}

__global__ void prep_nalu_kernel(const float* __restrict__ wh1, const float* __restrict__ mh1,
                                 const float* __restrict__ wh2, const float* __restrict__ mh2,
                                 float* __restrict__ W1, float* __restrict__ W2) {
  int i = blockIdx.x * 256 + threadIdx.x;
  if (i < 16384) {
    W1[i] = tanhf(wh1[i]) * (1.0f / (1.0f + expf(-mh1[i])));
  } else if (i < 18432) {
    int k = i - 16384;
    W2[k] = tanhf(wh2[k]) * (1.0f / (1.0f + expf(-mh2[k])));
  }
}

// ---------------- conv1: C_in=1, k=8 fp32 vector -> y1 fp8 + stats --------------
__global__ __launch_bounds__(256) void conv1_kernel(const float* __restrict__ inp,
                                                    const float* __restrict__ w1,
                                                    uint8_t* __restrict__ y1,
                                                    float* __restrict__ partials) {
  __shared__ float xsh[272];
  __shared__ float reds[2][8][128];
  const int tid = threadIdx.x;
  const int b = blockIdx.y;
  const int l0 = blockIdx.x * 256;
  const float* xb = inp + (size_t)b * 4096;
  for (int j = tid; j < 263; j += 256) {
    int li = l0 - 4 + j;
    xsh[j] = ((unsigned)li < 4096u) ? xb[li] : 0.f;
  }
  __syncthreads();
  const int cg = tid & 31, lsub = tid >> 5;
  float w[4][8];
#pragma unroll
  for (int ci = 0; ci < 4; ++ci)
#pragma unroll
    for (int t = 0; t < 8; ++t) w[ci][t] = w1[(cg * 4 + ci) * 8 + t];
  float s[4] = {0.f, 0.f, 0.f, 0.f}, q[4] = {0.f, 0.f, 0.f, 0.f};
  uint8_t* yb = y1 + ((size_t)b * LROWS + (ROW0 + l0)) * 128;
  for (int li = lsub; li < 256; li += 8) {
    if (l0 + li >= NVALID) break;
    unsigned pk = 0;
#pragma unroll
    for (int ci = 0; ci < 4; ++ci) {
      float a = 0.f;
#pragma unroll
      for (int t = 0; t < 8; ++t) a += xsh[li + t] * w[ci][t];
      s[ci] += a;
      q[ci] += a * a;
      pk |= (unsigned)f2fp8(a) << (8 * ci);
    }
    *(unsigned*)(yb + (size_t)li * 128 + cg * 4) = pk;
  }
#pragma unroll
  for (int ci = 0; ci < 4; ++ci) {
    reds[0][lsub][cg * 4 + ci] = s[ci];
    reds[1][lsub][cg * 4 + ci] = q[ci];
  }
  __syncthreads();
  if (tid < 128) {
    float ss = 0.f, qq = 0.f;
#pragma unroll
    for (int g = 0; g < 8; ++g) {
      ss += reds[0][g][tid];
      qq += reds[1][g][tid];
    }
    float* pb = partials + ((size_t)b * 17 + blockIdx.x) * 256;
    pb[tid] = ss;
    pb[128 + tid] = qq;
  }
}

// ---------------- BN finalize ---------------------------------------------------
__global__ __launch_bounds__(256) void finalize_kernel(const float* __restrict__ partials,
                                                       int nblk, int C,
                                                       const float* __restrict__ gamma,
                                                       const float* __restrict__ beta,
                                                       float* __restrict__ scale,
                                                       float* __restrict__ shift) {
  int c = blockIdx.x;
  float s = 0.f, q = 0.f;
  for (int i = threadIdx.x; i < nblk; i += 256) {
    const float* p = partials + (size_t)i * 2 * C;
    s += p[c];
    q += p[C + c];
  }
  __shared__ float rs[256], rq[256];
  rs[threadIdx.x] = s;
  rq[threadIdx.x] = q;
  __syncthreads();
  for (int st = 128; st > 0; st >>= 1) {
    if (threadIdx.x < st) {
      rs[threadIdx.x] += rs[threadIdx.x + st];
      rq[threadIdx.x] += rq[threadIdx.x + st];
    }
    __syncthreads();
  }
  if (threadIdx.x == 0) {
    const float N = 128.0f * 4097.0f;
    float mean = rs[0] / N;
    float var = rq[0] / N - mean * mean;
    float sc = gamma[c] * rsqrtf(var + 1e-5f);
    scale[c] = sc;
    shift[c] = beta[c] - mean * sc;
  }
}

// ---------------- conv2: 128ch -> 256ch, k=5, MFMA bf16 -------------------------
// block 128x256, 8 waves (2x4), wave 64x64. X LDS-resident; W chunk (32KB) LDS,
// reg-prefetched (T14: issue loads before MFMA cluster, ds_write after barrier).
__global__ __launch_bounds__(512, 2) void conv2_kernel(const uint8_t* __restrict__ y1,
                                                       const uint8_t* __restrict__ wp,
                                                       const float* __restrict__ s1,
                                                       const float* __restrict__ t1,
                                                       uint8_t* __restrict__ y2,
                                                       float* __restrict__ partials) {
  __shared__ uint4 xs4[2112];  // 132 rows x 256B, XOR-swizzled (33792 B)
  __shared__ uint4 wb4[2048];  // 32 KB weight chunk
  __shared__ float sred[4][256];
  uint8_t* xsb = (uint8_t*)xs4;
  uint8_t* wbuf = (uint8_t*)wb4;
  const int tid = threadIdx.x;
  const int b = blockIdx.y;
  const int l0 = blockIdx.x * 128;
  {
    const uint8_t* xrow = y1 + ((size_t)b * LROWS + (ROW0 + l0 - 2)) * 128;
    uint2 raw[5];
#pragma unroll
    for (int it = 0; it < 5; ++it) {
      int u = tid + it * 512;
      if (u < 2112) raw[it] = *(const uint2*)(xrow + (size_t)(u >> 4) * 128 + (u & 15) * 8);
    }
    uint4 wreg0[4];
#pragma unroll
    for (int i = 0; i < 4; ++i) wreg0[i] = *(const uint4*)(wp + (size_t)tid * 16 + i * 8192);
#pragma unroll
    for (int it = 0; it < 5; ++it) {
      int u = tid + it * 512;
      if (u < 2112) {
        int row = u >> 4, g8 = u & 15;
        bool valid = (unsigned)(l0 - 2 + row) < (unsigned)NVALID;
        uint4 p = stage8(raw[it], s1, t1, g8 * 8, valid);
        *(uint4*)(xsb + row * 256 + ((g8 * 16) ^ ((row & 7) << 4))) = p;
      }
    }
#pragma unroll
    for (int i = 0; i < 4; ++i) *(uint4*)(wbuf + tid * 16 + i * 8192) = wreg0[i];
  }
  __syncthreads();
  const int lane = tid & 63, wid = tid >> 6;
  const int wr = wid >> 2, wc = wid & 3;
  const int lrow = lane & 15, lk = lane >> 4;
  const int r0 = wr * 64, c0 = wc * 64;
  f32x4 acc[4][4] = {};
  uint4 wreg[4];
  for (int c = 0; c < 10; ++c) {
    if (c < 9) {  // issue next-chunk loads; latency hidden under MFMAs below
      const uint8_t* wsrc = wp + (size_t)(c + 1) * 32768;
#pragma unroll
      for (int i = 0; i < 4; ++i) wreg[i] = *(const uint4*)(wsrc + (size_t)tid * 16 + i * 8192);
    }
    const int t = c >> 1;
#pragma unroll
    for (int ks = 0; ks < 2; ++ks) {
      const int kk = (c & 1) * 2 + ks;
      bf16x8 a[4], bb[4];
#pragma unroll
      for (int fr = 0; fr < 4; ++fr) {
        int row = r0 + fr * 16 + lrow + t;
        a[fr] = *(const bf16x8*)(xsb + row * 256 + ((kk * 64 + lk * 16) ^ ((row & 7) << 4)));
      }
#pragma unroll
      for (int fc = 0; fc < 4; ++fc)
        bb[fc] = *(const bf16x8*)(wbuf + ks * 16384 + (wc * 4 + fc) * 1024 + lane * 16);
#pragma unroll
      for (int fr = 0; fr < 4; ++fr)
#pragma unroll
        for (int fc = 0; fc < 4; ++fc)
          acc[fr][fc] = __builtin_amdgcn_mfma_f32_16x16x32_bf16(a[fr], bb[fc], acc[fr][fc], 0, 0, 0);
    }
    __syncthreads();
    if (c < 9) {
#pragma unroll
      for (int i = 0; i < 4; ++i) *(uint4*)(wbuf + tid * 16 + i * 8192) = wreg[i];
      __syncthreads();
    }
  }
  // epilogue: fp8 into (dead) X LDS, coalesced store + fp32 stats partials
  float ps[4] = {0.f, 0.f, 0.f, 0.f}, pq[4] = {0.f, 0.f, 0.f, 0.f};
#pragma unroll
  for (int fr = 0; fr < 4; ++fr)
#pragma unroll
    for (int fc = 0; fc < 4; ++fc) {
      int col = c0 + fc * 16 + lrow;
#pragma unroll
      for (int rg = 0; rg < 4; ++rg) {
        int r = r0 + fr * 16 + lk * 4 + rg;
        float v = acc[fr][fc][rg];
        xsb[r * 256 + col] = f2fp8(v);
        if (l0 + r < NVALID) {
          ps[fc] += v;
          pq[fc] += v * v;
        }
      }
    }
#pragma unroll
  for (int fc = 0; fc < 4; ++fc) {
    float s = ps[fc], q = pq[fc];
    s += __shfl_xor(s, 16); s += __shfl_xor(s, 32);
    q += __shfl_xor(q, 16); q += __shfl_xor(q, 32);
    if (lk == 0) {
      int col = c0 + fc * 16 + lrow;
      sred[wr * 2 + 0][col] = s;
      sred[wr * 2 + 1][col] = q;
    }
  }
  __syncthreads();
  {
    uint8_t* yb = y2 + ((size_t)b * LROWS + (ROW0 + l0)) * 256;
    int row = tid >> 2, q = tid & 3;
    const uint8_t* src = xsb + row * 256 + q * 64;
    uint8_t* dst = yb + (size_t)row * 256 + q * 64;
    uint4 v0 = *(const uint4*)(src);
    uint4 v1 = *(const uint4*)(src + 16);
    uint4 v2 = *(const uint4*)(src + 32);
    uint4 v3 = *(const uint4*)(src + 48);
    *(uint4*)(dst) = v0;
    *(uint4*)(dst + 16) = v1;
    *(uint4*)(dst + 32) = v2;
    *(uint4*)(dst + 48) = v3;
  }
  if (tid < 256) {
    float* pb = partials + ((size_t)b * 33 + blockIdx.x) * 512;
    pb[tid] = sred[0][tid] + sred[2][tid];
    pb[256 + tid] = sred[1][tid] + sred[3][tid];
  }
}

// ---------------- conv3: 256ch -> 128ch, k=3, MFMA bf16, 2 channel-halves -------
// block 128x128, 8 waves (2x4), wave 64x32; W chunk (16KB) LDS reg-prefetched.
__global__ __launch_bounds__(512, 4) void conv3_kernel(const uint8_t* __restrict__ y2,
                                                       const uint8_t* __restrict__ wp,
                                                       const float* __restrict__ s2,
                                                       const float* __restrict__ t2,
                                                       uint8_t* __restrict__ y3,
                                                       float* __restrict__ partials) {
  __shared__ uint4 xs4[2080];  // 130 rows x 256B (one 128-ch half), swizzled
  __shared__ uint4 wb4[1024];  // 16 KB weight chunk
  __shared__ float sred[4][128];
  uint8_t* xsb = (uint8_t*)xs4;
  uint8_t* wbuf = (uint8_t*)wb4;
  const int tid = threadIdx.x;
  const int b = blockIdx.y;
  const int l0 = blockIdx.x * 128;
  const int lane = tid & 63, wid = tid >> 6;
  const int wr = wid >> 2, wc = wid & 3;
  const int lrow = lane & 15, lk = lane >> 4;
  const int r0 = wr * 64, c0 = wc * 32;
  const uint8_t* xrowbase = y2 + ((size_t)b * LROWS + (ROW0 + l0 - 1)) * 256;
  // chunk cc in 0..11: h=cc/6, r=cc%6, t=r>>1, k2=r&1; base=(t*8+h*4+k2*2)*8192
  auto wbase = [](int cc) {
    int h = cc / 6, r = cc % 6;
    return (size_t)((r >> 1) * 8 + h * 4 + (r & 1) * 2) * 8192;
  };
  f32x4 acc[4][2] = {};
  uint2 raw[5];
  uint4 wreg[2];
  // ---- stage half-0 X + W chunk 0
#pragma unroll
  for (int it = 0; it < 5; ++it) {
    int u = tid + it * 512;
    if (u < 2080) raw[it] = *(const uint2*)(xrowbase + (size_t)(u >> 4) * 256 + (u & 15) * 8);
  }
#pragma unroll
  for (int i = 0; i < 2; ++i) wreg[i] = *(const uint4*)(wp + (size_t)tid * 16 + i * 8192);
#pragma unroll
  for (int it = 0; it < 5; ++it) {
    int u = tid + it * 512;
    if (u < 2080) {
      int row = u >> 4, g8 = u & 15;
      bool valid = (unsigned)(l0 - 1 + row) < (unsigned)NVALID;
      uint4 p = stage8(raw[it], s2, t2, g8 * 8, valid);
      *(uint4*)(xsb + row * 256 + ((g8 * 16) ^ ((row & 7) << 4))) = p;
    }
  }
#pragma unroll
  for (int i = 0; i < 2; ++i) *(uint4*)(wbuf + tid * 16 + i * 8192) = wreg[i];
  __syncthreads();
  // ---- issue half-1 X loads early (hide HBM latency under half-0 compute)
#pragma unroll
  for (int it = 0; it < 5; ++it) {
    int u = tid + it * 512;
    if (u < 2080) raw[it] = *(const uint2*)(xrowbase + (size_t)(u >> 4) * 256 + 128 + (u & 15) * 8);
  }
#define C3CHUNK(CC)                                                                \
  {                                                                                \
    const int t_ = ((CC) % 6) >> 1, k2_ = (CC) & 1;                                \
    _Pragma("unroll") for (int ks = 0; ks < 2; ++ks) {                             \
      bf16x8 a[4], bb[2];                                                          \
      _Pragma("unroll") for (int fr = 0; fr < 4; ++fr) {                           \
        int row = r0 + fr * 16 + lrow + t_;                                        \
        a[fr] = *(const bf16x8*)(xsb + row * 256 +                                 \
                                 ((k2_ * 128 + ks * 64 + lk * 16) ^ ((row & 7) << 4))); \
      }                                                                            \
      _Pragma("unroll") for (int fc = 0; fc < 2; ++fc)                             \
          bb[fc] = *(const bf16x8*)(wbuf + ks * 8192 + (wc * 2 + fc) * 1024 + lane * 16); \
      _Pragma("unroll") for (int fr = 0; fr < 4; ++fr)                             \
          _Pragma("unroll") for (int fc = 0; fc < 2; ++fc)                         \
              acc[fr][fc] = __builtin_amdgcn_mfma_f32_16x16x32_bf16(               \
                  a[fr], bb[fc], acc[fr][fc], 0, 0, 0);                            \
    }                                                                              \
  }
  // ---- half-0 chunks (0..5); prefetch cc+1 (incl. half-1's first chunk)
  for (int cc = 0; cc < 6; ++cc) {
    const uint8_t* wsrc = wp + wbase(cc + 1);
#pragma unroll
    for (int i = 0; i < 2; ++i) wreg[i] = *(const uint4*)(wsrc + (size_t)tid * 16 + i * 8192);
    C3CHUNK(cc);
    __syncthreads();
#pragma unroll
    for (int i = 0; i < 2; ++i) *(uint4*)(wbuf + tid * 16 + i * 8192) = wreg[i];
    __syncthreads();
  }
  // ---- decode + write half-1 X (xsb free after the barrier above)
#pragma unroll
  for (int it = 0; it < 5; ++it) {
    int u = tid + it * 512;
    if (u < 2080) {
      int row = u >> 4, g8 = u & 15;
      bool valid = (unsigned)(l0 - 1 + row) < (unsigned)NVALID;
      uint4 p = stage8(raw[it], s2, t2, 128 + g8 * 8, valid);
      *(uint4*)(xsb + row * 256 + ((g8 * 16) ^ ((row & 7) << 4))) = p;
    }
  }
  __syncthreads();
  // ---- half-1 chunks (6..11)
  for (int cc = 6; cc < 12; ++cc) {
    if (cc < 11) {
      const uint8_t* wsrc = wp + wbase(cc + 1);
#pragma unroll
      for (int i = 0; i < 2; ++i) wreg[i] = *(const uint4*)(wsrc + (size_t)tid * 16 + i * 8192);
    }
    C3CHUNK(cc);
    __syncthreads();
    if (cc < 11) {
#pragma unroll
      for (int i = 0; i < 2; ++i) *(uint4*)(wbuf + tid * 16 + i * 8192) = wreg[i];
      __syncthreads();
    }
  }
  // epilogue
  float ps[2] = {0.f, 0.f}, pq[2] = {0.f, 0.f};
#pragma unroll
  for (int fr = 0; fr < 4; ++fr)
#pragma unroll
    for (int fc = 0; fc < 2; ++fc) {
      int col = c0 + fc * 16 + lrow;
#pragma unroll
      for (int rg = 0; rg < 4; ++rg) {
        int r = r0 + fr * 16 + lk * 4 + rg;
        float v = acc[fr][fc][rg];
        xsb[r * 128 + col] = f2fp8(v);
        if (l0 + r < NVALID) {
          ps[fc] += v;
          pq[fc] += v * v;
        }
      }
    }
#pragma unroll
  for (int fc = 0; fc < 2; ++fc) {
    float s = ps[fc], q = pq[fc];
    s += __shfl_xor(s, 16); s += __shfl_xor(s, 32);
    q += __shfl_xor(q, 16); q += __shfl_xor(q, 32);
    if (lk == 0) {
      int col = c0 + fc * 16 + lrow;
      sred[wr * 2 + 0][col] = s;
      sred[wr * 2 + 1][col] = q;
    }
  }
  __syncthreads();
  {
    uint8_t* yb = y3 + ((size_t)b * LROWS + (ROW0 + l0)) * 128;
    int row = tid >> 2, q = tid & 3;
    const uint8_t* src = xsb + row * 128 + q * 32;
    uint8_t* dst = yb + (size_t)row * 128 + q * 32;
    uint4 v0 = *(const uint4*)(src);
    uint4 v1 = *(const uint4*)(src + 16);
    *(uint4*)(dst) = v0;
    *(uint4*)(dst + 16) = v1;
  }
  if (tid < 128) {
    float* pb = partials + ((size_t)b * 33 + blockIdx.x) * 256;
    pb[tid] = sred[0][tid] + sred[2][tid];
    pb[128 + tid] = sred[1][tid] + sred[3][tid];
  }
}

// ---------------- feat: BN3+ReLU fused into length-mean partials ----------------
__global__ __launch_bounds__(256) void feat_kernel(const uint8_t* __restrict__ y3,
                                                   const float* __restrict__ s3,
                                                   const float* __restrict__ t3,
                                                   float* __restrict__ fpart) {
  const int b = blockIdx.y, chk = blockIdx.x;
  const int cq = threadIdx.x & 31, lg = threadIdx.x >> 5;
  const uint8_t* base = y3 + ((size_t)b * LROWS + ROW0) * 128;
  float sc[4], sh[4], acc[4] = {0.f, 0.f, 0.f, 0.f};
#pragma unroll
  for (int ci = 0; ci < 4; ++ci) {
    sc[ci] = s3[cq * 4 + ci];
    sh[ci] = t3[cq * 4 + ci];
  }
  int lstart = chk * 513, lend = lstart + 513;
  if (lend > NVALID) lend = NVALID;
  for (int l = lstart + lg; l < lend; l += 8) {
    unsigned u = *(const unsigned*)(base + (size_t)l * 128 + cq * 4);
#pragma unroll
    for (int ci = 0; ci < 4; ++ci)
      acc[ci] += fmaxf(fp82f((u >> (8 * ci)) & 0xffu) * sc[ci] + sh[ci], 0.f);
  }
  __shared__ float red[8][128];
#pragma unroll
  for (int ci = 0; ci < 4; ++ci) red[lg][cq * 4 + ci] = acc[ci];
  __syncthreads();
  if (threadIdx.x < 128) {
    float sum = 0.f;
#pragma unroll
    for (int g = 0; g < 8; ++g) sum += red[g][threadIdx.x];
    fpart[((size_t)chk * 128 + b) * 128 + threadIdx.x] = sum;
  }
}

// ---------------- head: NALU x2 + final linear (fp32) ---------------------------
__global__ __launch_bounds__(128) void head_kernel(const float* __restrict__ fpart,
                                                   const float* __restrict__ W1,
                                                   const float* __restrict__ G1,
                                                   const float* __restrict__ W2,
                                                   const float* __restrict__ G2,
                                                   const float* __restrict__ fw,
                                                   const float* __restrict__ fb,
                                                   float* __restrict__ out) {
  const int b = blockIdx.x, j = threadIdx.x;
  __shared__ float xs[128], lxs[128], h1[128], lh1[128], h2[16];
  float x = 0.f;
#pragma unroll
  for (int chk = 0; chk < 8; ++chk) x += fpart[((size_t)chk * 128 + b) * 128 + j];
  x *= (1.0f / 4097.0f);
  xs[j] = x;
  lxs[j] = logf(fabsf(x) + 1e-10f);
  __syncthreads();
  float a = 0.f, me = 0.f, ga = 0.f;
  for (int i = 0; i < 128; ++i) {
    float w = W1[j * 128 + i];
    a += xs[i] * w;
    me += lxs[i] * w;
    ga += xs[i] * G1[j * 128 + i];
  }
  float g = 1.0f / (1.0f + expf(-ga));
  float h = g * a + (1.0f - g) * expf(me);
  h1[j] = h;
  lh1[j] = logf(fabsf(h) + 1e-10f);
  __syncthreads();
  if (j < 16) {
    float a2 = 0.f, m2 = 0.f, g2 = 0.f;
    for (int i = 0; i < 128; ++i) {
      float w = W2[j * 128 + i];
      a2 += h1[i] * w;
      m2 += lh1[i] * w;
      g2 += h1[i] * G2[j * 128 + i];
    }
    float gg = 1.0f / (1.0f + expf(-g2));
    h2[j] = gg * a2 + (1.0f - gg) * expf(m2);
  }
  __syncthreads();
  if (j == 0) {
    float o = fb[0];
#pragma unroll
    for (int i = 0; i < 16; ++i) o += h2[i] * fw[i];
    out[b] = o;
  }
}

// ---------------- launch --------------------------------------------------------
extern "C" void kernel_launch(void* const* d_in, const int* in_sizes, int n_in,
                              void* d_out, int out_size, void* d_ws, size_t ws_size,
                              hipStream_t stream) {
  (void)in_sizes; (void)n_in; (void)out_size; (void)ws_size;
  const float* inp = (const float*)d_in[0];
  const float* w1  = (const float*)d_in[1];
  const float* g1  = (const float*)d_in[3];
  const float* b1  = (const float*)d_in[4];
  const float* w2  = (const float*)d_in[5];
  const float* g2  = (const float*)d_in[7];
  const float* b2  = (const float*)d_in[8];
  const float* w3  = (const float*)d_in[9];
  const float* g3  = (const float*)d_in[11];
  const float* b3  = (const float*)d_in[12];
  const float* wh1 = (const float*)d_in[13];
  const float* mh1 = (const float*)d_in[14];
  const float* G1  = (const float*)d_in[15];
  const float* wh2 = (const float*)d_in[16];
  const float* mh2 = (const float*)d_in[17];
  const float* G2  = (const float*)d_in[18];
  const float* fw  = (const float*)d_in[19];
  const float* fb  = (const float*)d_in[20];
  float* out = (float*)d_out;

  uint8_t* ws = (uint8_t*)d_ws;
  size_t off = 0;
  auto alloc = [&](size_t n) {
    uint8_t* p = ws + off;
    off += (n + 255) & ~(size_t)255;
    return p;
  };
  uint8_t* y1  = alloc((size_t)128 * LROWS * 128);   // fp8; later aliased as y3
  uint8_t* y2  = alloc((size_t)128 * LROWS * 256);   // fp8
  uint8_t* w2p = alloc((size_t)320 * 1024);
  uint8_t* w3p = alloc((size_t)192 * 1024);
  float* part1 = (float*)alloc((size_t)2176 * 256 * 4);
  float* part2 = (float*)alloc((size_t)4224 * 512 * 4);
  float* part3 = (float*)alloc((size_t)4224 * 256 * 4);
  float* s1 = (float*)alloc(128 * 4); float* t1 = (float*)alloc(128 * 4);
  float* s2 = (float*)alloc(256 * 4); float* t2 = (float*)alloc(256 * 4);
  float* s3 = (float*)alloc(128 * 4); float* t3 = (float*)alloc(128 * 4);
  float* fpart = (float*)alloc((size_t)8 * 128 * 128 * 4);
  float* W1n = (float*)alloc(128 * 128 * 4);
  float* W2n = (float*)alloc(16 * 128 * 4);
  uint8_t* y3 = y1;  // alias: y1 dead once conv2 done

  prepack_w2_kernel<<<640, 256, 0, stream>>>(w2, w2p);
  prepack_w3_kernel<<<384, 256, 0, stream>>>(w3, w3p);
  prep_nalu_kernel<<<72, 256, 0, stream>>>(wh1, mh1, wh2, mh2, W1n, W2n);

  conv1_kernel<<<dim3(17, 128), 256, 0, stream>>>(inp, w1, y1, part1);
  finalize_kernel<<<128, 256, 0, stream>>>(part1, 2176, 128, g1, b1, s1, t1);

  conv2_kernel<<<dim3(33, 128), 512, 0, stream>>>(y1, w2p, s1, t1, y2, part2);
  finalize_kernel<<<256, 256, 0, stream>>>(part2, 4224, 256, g2, b2, s2, t2);

  conv3_kernel<<<dim3(33, 128), 512, 0, stream>>>(y2, w3p, s2, t2, y3, part3);
  finalize_kernel<<<128, 256, 0, stream>>>(part3, 4224, 128, g3, b3, s3, t3);

  feat_kernel<<<dim3(8, 128), 256, 0, stream>>>(y3, s3, t3, fpart);
  head_kernel<<<128, 128, 0, stream>>>(fpart, W1n, G1, W2n, G2, fw, fb, out);
}

// Round 6
// 1433.491 us; speedup vs baseline: 1.1520x; 1.1520x over previous
//
#include <hip/hip_runtime.h>
#include <stdint.h>

#define LROWS 4240
#define ROW0 8
#define NVALID 4097

typedef float f32x4 __attribute__((ext_vector_type(4)));
typedef short bf16x8 __attribute__((ext_vector_type(8)));

#define GLOAD_LDS(gaddr, laddr)                                                            \
  __builtin_amdgcn_global_load_lds((const __attribute__((address_space(1))) void*)(gaddr), \
                                   (__attribute__((address_space(3))) void*)(laddr), 16, 0, 0)

__device__ __forceinline__ unsigned short f2bf(float f) {
  unsigned u = __float_as_uint(f);
  u += 0x7fffu + ((u >> 16) & 1u);
  return (unsigned short)(u >> 16);
}
__device__ __forceinline__ float bf2f(unsigned short h) {
  return __uint_as_float(((unsigned)h) << 16);
}
// OCP e4m3fn codec via exponent-shift trick (exact, incl. subnormals, RNE)
__device__ __forceinline__ uint8_t f2fp8(float f) {
  f = fminf(fmaxf(f, -448.f), 448.f);
  unsigned u = __float_as_uint(f * 0x1p-120f);
  unsigned s = (u >> 24) & 0x80u;
  u &= 0x7fffffffu;
  u += 0x7ffffu + ((u >> 20) & 1u);
  return (uint8_t)(s | (u >> 20));
}
__device__ __forceinline__ float fp82f(unsigned b) {
  return __uint_as_float(((b & 0x80u) << 24) | ((b & 0x7fu) << 20)) * 0x1p120f;
}

// decode 8 fp8 + BN + ReLU -> 8 bf16 packed in uint4 (zero if !valid)
__device__ __forceinline__ uint4 stage8(uint2 raw, const float* __restrict__ sc,
                                        const float* __restrict__ sh, int c0, bool valid) {
  unsigned short o[8];
#pragma unroll
  for (int j = 0; j < 8; ++j) {
    float f = 0.f;
    if (valid) {
      unsigned byte = ((j < 4 ? raw.x : raw.y) >> (8 * (j & 3))) & 0xffu;
      f = fmaxf(fp82f(byte) * sc[c0 + j] + sh[c0 + j], 0.f);
    }
    o[j] = f2bf(f);
  }
  return make_uint4((unsigned)o[0] | ((unsigned)o[1] << 16),
                    (unsigned)o[2] | ((unsigned)o[3] << 16),
                    (unsigned)o[4] | ((unsigned)o[5] << 16),
                    (unsigned)o[6] | ((unsigned)o[7] << 16));
}

// ---------------- weight prepack: per-(K-step, colgroup) 1KB fragment blobs ----
// conv2: step = t*4 + (cin>>5) (20 steps x 16 og-blobs); 8KB half-chunks.
__global__ void prepack_w2_kernel(const float* __restrict__ w2, uint8_t* __restrict__ wp) {
  int i = blockIdx.x * 256 + threadIdx.x;
  if (i >= 163840) return;
  int t = i % 5, oc = i / 5;
  int cin = oc & 127, o = oc >> 7;
  int step = t * 4 + (cin >> 5);
  int og = o >> 4;
  int lane = ((cin >> 3) & 3) * 16 + (o & 15);
  int j = cin & 7;
  *(unsigned short*)(wp + ((size_t)(step * 16 + og) << 10) + lane * 16 + j * 2) = f2bf(w2[i]);
}
// conv3: step = t*8 + (cin>>5) (24 steps x 8 og-blobs = 8KB chunks).
__global__ void prepack_w3_kernel(const float* __restrict__ w3, uint8_t* __restrict__ wp) {
  int i = blockIdx.x * 256 + threadIdx.x;
  if (i >= 98304) return;
  int t = i % 3, oc = i / 3;
  int cin = oc & 255, o = oc >> 8;
  int step = t * 8 + (cin >> 5);
  int og = o >> 4;
  int lane = ((cin >> 3) & 3) * 16 + (o & 15);
  int j = cin & 7;
  *(unsigned short*)(wp + ((size_t)(step * 8 + og) << 10) + lane * 16 + j * 2) = f2bf(w3[i]);
}

__global__ void prep_nalu_kernel(const float* __restrict__ wh1, const float* __restrict__ mh1,
                                 const float* __restrict__ wh2, const float* __restrict__ mh2,
                                 float* __restrict__ W1, float* __restrict__ W2) {
  int i = blockIdx.x * 256 + threadIdx.x;
  if (i < 16384) {
    W1[i] = tanhf(wh1[i]) * (1.0f / (1.0f + expf(-mh1[i])));
  } else if (i < 18432) {
    int k = i - 16384;
    W2[k] = tanhf(wh2[k]) * (1.0f / (1.0f + expf(-mh2[k])));
  }
}

// ---------------- conv1: C_in=1, k=8 fp32 vector -> y1 fp8 + stats --------------
__global__ __launch_bounds__(256) void conv1_kernel(const float* __restrict__ inp,
                                                    const float* __restrict__ w1,
                                                    uint8_t* __restrict__ y1,
                                                    float* __restrict__ partials) {
  __shared__ float xsh[272];
  __shared__ float reds[2][8][128];
  const int tid = threadIdx.x;
  const int b = blockIdx.y;
  const int l0 = blockIdx.x * 256;
  const float* xb = inp + (size_t)b * 4096;
  for (int j = tid; j < 263; j += 256) {
    int li = l0 - 4 + j;
    xsh[j] = ((unsigned)li < 4096u) ? xb[li] : 0.f;
  }
  __syncthreads();
  const int cg = tid & 31, lsub = tid >> 5;
  float w[4][8];
#pragma unroll
  for (int ci = 0; ci < 4; ++ci)
#pragma unroll
    for (int t = 0; t < 8; ++t) w[ci][t] = w1[(cg * 4 + ci) * 8 + t];
  float s[4] = {0.f, 0.f, 0.f, 0.f}, q[4] = {0.f, 0.f, 0.f, 0.f};
  uint8_t* yb = y1 + ((size_t)b * LROWS + (ROW0 + l0)) * 128;
  for (int li = lsub; li < 256; li += 8) {
    if (l0 + li >= NVALID) break;
    unsigned pk = 0;
#pragma unroll
    for (int ci = 0; ci < 4; ++ci) {
      float a = 0.f;
#pragma unroll
      for (int t = 0; t < 8; ++t) a += xsh[li + t] * w[ci][t];
      s[ci] += a;
      q[ci] += a * a;
      pk |= (unsigned)f2fp8(a) << (8 * ci);
    }
    *(unsigned*)(yb + (size_t)li * 128 + cg * 4) = pk;
  }
#pragma unroll
  for (int ci = 0; ci < 4; ++ci) {
    reds[0][lsub][cg * 4 + ci] = s[ci];
    reds[1][lsub][cg * 4 + ci] = q[ci];
  }
  __syncthreads();
  if (tid < 128) {
    float ss = 0.f, qq = 0.f;
#pragma unroll
    for (int g = 0; g < 8; ++g) {
      ss += reds[0][g][tid];
      qq += reds[1][g][tid];
    }
    float* pb = partials + ((size_t)b * 17 + blockIdx.x) * 256;
    pb[tid] = ss;
    pb[128 + tid] = qq;
  }
}

// ---------------- BN finalize ---------------------------------------------------
__global__ __launch_bounds__(256) void finalize_kernel(const float* __restrict__ partials,
                                                       int nblk, int C,
                                                       const float* __restrict__ gamma,
                                                       const float* __restrict__ beta,
                                                       float* __restrict__ scale,
                                                       float* __restrict__ shift) {
  int c = blockIdx.x;
  float s = 0.f, q = 0.f;
  for (int i = threadIdx.x; i < nblk; i += 256) {
    const float* p = partials + (size_t)i * 2 * C;
    s += p[c];
    q += p[C + c];
  }
  __shared__ float rs[256], rq[256];
  rs[threadIdx.x] = s;
  rq[threadIdx.x] = q;
  __syncthreads();
  for (int st = 128; st > 0; st >>= 1) {
    if (threadIdx.x < st) {
      rs[threadIdx.x] += rs[threadIdx.x + st];
      rq[threadIdx.x] += rq[threadIdx.x + st];
    }
    __syncthreads();
  }
  if (threadIdx.x == 0) {
    const float N = 128.0f * 4097.0f;
    float mean = rs[0] / N;
    float var = rq[0] / N - mean * mean;
    float sc = gamma[c] * rsqrtf(var + 1e-5f);
    scale[c] = sc;
    shift[c] = beta[c] - mean * sc;
  }
}

// ---------------- conv2: m97-clone. 256 thr, 4 waves (2x2), wave 64x64 ----------
// tile 128 rows x 128 cout (cout-half = blockIdx.y); 20 chunks of BK=32.
// W: LDS dbuf 2x8KB via global_load_lds; X: bf16 LDS-resident, XOR-swizzled.
__global__ __launch_bounds__(256, 2) void conv2_kernel(const uint8_t* __restrict__ y1,
                                                       const uint8_t* __restrict__ wp,
                                                       const float* __restrict__ s1,
                                                       const float* __restrict__ t1,
                                                       uint8_t* __restrict__ y2,
                                                       float* __restrict__ partials) {
  __shared__ uint4 xs4[2112];  // 132 rows x 256B bf16, XOR-swizzled
  __shared__ uint4 wb4[1024];  // 2 x 8KB weight chunks
  __shared__ float sred[2][2][128];
  uint8_t* xsb = (uint8_t*)xs4;
  uint8_t* wbuf = (uint8_t*)wb4;
  const int tid = threadIdx.x;
  const int b = blockIdx.z;
  const int h2 = blockIdx.y;
  const int l0 = blockIdx.x * 128;
  const uint8_t* wph = wp + (size_t)h2 * 8192;
  // prologue: async-stage W chunk 0 + reg-stage X (fp8 -> BN+ReLU -> bf16)
  GLOAD_LDS(wph + tid * 16, wbuf + tid * 16);
  GLOAD_LDS(wph + 4096 + tid * 16, wbuf + 4096 + tid * 16);
  {
    const uint8_t* xrow = y1 + ((size_t)b * LROWS + (ROW0 + l0 - 2)) * 128;
    uint2 raw[9];
#pragma unroll
    for (int it = 0; it < 9; ++it) {
      int u = tid + it * 256;
      if (u < 2112) raw[it] = *(const uint2*)(xrow + (size_t)(u >> 4) * 128 + (u & 15) * 8);
    }
#pragma unroll
    for (int it = 0; it < 9; ++it) {
      int u = tid + it * 256;
      if (u < 2112) {
        int row = u >> 4, g8 = u & 15;
        bool valid = (unsigned)(l0 - 2 + row) < (unsigned)NVALID;
        uint4 p = stage8(raw[it], s1, t1, g8 * 8, valid);
        *(uint4*)(xsb + row * 256 + ((g8 * 16) ^ ((row & 7) << 4))) = p;
      }
    }
  }
  __syncthreads();
  const int lane = tid & 63, wid = tid >> 6;
  const int wr = wid >> 1, wcc = wid & 1;
  const int lrow = lane & 15, lk = lane >> 4;
  const int r0 = wr * 64, c0 = wcc * 64;
  f32x4 acc[4][4] = {};
  for (int s = 0; s < 20; ++s) {
    if (s < 19) {  // async prefetch next W chunk; completes at this chunk's barrier
      const uint8_t* src = wph + (size_t)(s + 1) * 16384;
      uint8_t* dst = wbuf + ((s + 1) & 1) * 8192;
      GLOAD_LDS(src + tid * 16, dst + tid * 16);
      GLOAD_LDS(src + 4096 + tid * 16, dst + 4096 + tid * 16);
    }
    const int t = s >> 2, kk = s & 3;
    bf16x8 a[4], bb[4];
#pragma unroll
    for (int fr = 0; fr < 4; ++fr) {
      int row = r0 + fr * 16 + lrow + t;
      a[fr] = *(const bf16x8*)(xsb + row * 256 + ((kk * 64 + lk * 16) ^ ((row & 7) << 4)));
    }
    const uint8_t* wc = wbuf + (s & 1) * 8192 + (wcc * 4) * 1024 + (size_t)lane * 16;
#pragma unroll
    for (int fc = 0; fc < 4; ++fc) bb[fc] = *(const bf16x8*)(wc + fc * 1024);
#pragma unroll
    for (int fr = 0; fr < 4; ++fr)
#pragma unroll
      for (int fc = 0; fc < 4; ++fc)
        acc[fr][fc] = __builtin_amdgcn_mfma_f32_16x16x32_bf16(a[fr], bb[fc], acc[fr][fc], 0, 0, 0);
    __syncthreads();
  }
  // epilogue: fp8 into dead X LDS + stats; coalesced store
  float ps[4] = {0.f, 0.f, 0.f, 0.f}, pq[4] = {0.f, 0.f, 0.f, 0.f};
#pragma unroll
  for (int fr = 0; fr < 4; ++fr)
#pragma unroll
    for (int fc = 0; fc < 4; ++fc) {
      int col = c0 + fc * 16 + lrow;
#pragma unroll
      for (int rg = 0; rg < 4; ++rg) {
        int r = r0 + fr * 16 + lk * 4 + rg;
        float v = acc[fr][fc][rg];
        xsb[r * 128 + col] = f2fp8(v);
        if (l0 + r < NVALID) {
          ps[fc] += v;
          pq[fc] += v * v;
        }
      }
    }
#pragma unroll
  for (int fc = 0; fc < 4; ++fc) {
    float s = ps[fc], q = pq[fc];
    s += __shfl_xor(s, 16); s += __shfl_xor(s, 32);
    q += __shfl_xor(q, 16); q += __shfl_xor(q, 32);
    if (lk == 0) {
      int col = c0 + fc * 16 + lrow;
      sred[wr][0][col] = s;
      sred[wr][1][col] = q;
    }
  }
  __syncthreads();
  {
    uint8_t* yb = y2 + ((size_t)b * LROWS + (ROW0 + l0)) * 256 + h2 * 128;
    int row = tid >> 1, q = tid & 1;
    const uint8_t* src = xsb + row * 128 + q * 64;
    uint8_t* dst = yb + (size_t)row * 256 + q * 64;
    uint4 v0 = *(const uint4*)(src);
    uint4 v1 = *(const uint4*)(src + 16);
    uint4 v2 = *(const uint4*)(src + 32);
    uint4 v3 = *(const uint4*)(src + 48);
    *(uint4*)(dst) = v0;
    *(uint4*)(dst + 16) = v1;
    *(uint4*)(dst + 32) = v2;
    *(uint4*)(dst + 48) = v3;
  }
  if (tid < 128) {
    float* pb = partials + ((size_t)b * 33 + blockIdx.x) * 512;
    pb[h2 * 128 + tid] = sred[0][0][tid] + sred[1][0][tid];
    pb[256 + h2 * 128 + tid] = sred[0][1][tid] + sred[1][1][tid];
  }
}

// ---------------- conv3: m97-clone. 256 thr, wave 64x64, tile 128x128 -----------
// K = 256ch x 3 taps = 24 chunks of BK=32; X restaged per 128-ch half.
__global__ __launch_bounds__(256, 2) void conv3_kernel(const uint8_t* __restrict__ y2,
                                                       const uint8_t* __restrict__ wp,
                                                       const float* __restrict__ s2,
                                                       const float* __restrict__ t2,
                                                       uint8_t* __restrict__ y3,
                                                       float* __restrict__ partials) {
  __shared__ uint4 xs4[2080];  // 130 rows x 256B (one 128-ch half), swizzled
  __shared__ uint4 wb4[1024];  // 2 x 8KB
  __shared__ float sred[2][2][128];
  uint8_t* xsb = (uint8_t*)xs4;
  uint8_t* wbuf = (uint8_t*)wb4;
  const int tid = threadIdx.x;
  const int b = blockIdx.z;
  const int l0 = blockIdx.x * 128;
  const uint8_t* xrowbase = y2 + ((size_t)b * LROWS + (ROW0 + l0 - 1)) * 256;
  // prologue: W chunk 0 + X half-0
  GLOAD_LDS(wp + tid * 16, wbuf + tid * 16);
  GLOAD_LDS(wp + 4096 + tid * 16, wbuf + 4096 + tid * 16);
  {
    uint2 raw[9];
#pragma unroll
    for (int it = 0; it < 9; ++it) {
      int u = tid + it * 256;
      if (u < 2080) raw[it] = *(const uint2*)(xrowbase + (size_t)(u >> 4) * 256 + (u & 15) * 8);
    }
#pragma unroll
    for (int it = 0; it < 9; ++it) {
      int u = tid + it * 256;
      if (u < 2080) {
        int row = u >> 4, g8 = u & 15;
        bool valid = (unsigned)(l0 - 1 + row) < (unsigned)NVALID;
        uint4 p = stage8(raw[it], s2, t2, g8 * 8, valid);
        *(uint4*)(xsb + row * 256 + ((g8 * 16) ^ ((row & 7) << 4))) = p;
      }
    }
  }
  __syncthreads();
  const int lane = tid & 63, wid = tid >> 6;
  const int wr = wid >> 1, wcc = wid & 1;
  const int lrow = lane & 15, lk = lane >> 4;
  const int r0 = wr * 64, c0 = wcc * 64;
  f32x4 acc[4][4] = {};
  for (int i = 0; i < 24; ++i) {
    if (i < 23) {
      int n = i + 1, hn = n / 12, rn = n % 12;
      const uint8_t* src = wp + (size_t)((rn >> 2) * 8 + hn * 4 + (rn & 3)) * 8192;
      uint8_t* dst = wbuf + (n & 1) * 8192;
      GLOAD_LDS(src + tid * 16, dst + tid * 16);
      GLOAD_LDS(src + 4096 + tid * 16, dst + 4096 + tid * 16);
    }
    const int t = (i % 12) >> 2, kq = i & 3;
    bf16x8 a[4], bb[4];
#pragma unroll
    for (int fr = 0; fr < 4; ++fr) {
      int row = r0 + fr * 16 + lrow + t;
      a[fr] = *(const bf16x8*)(xsb + row * 256 + ((kq * 64 + lk * 16) ^ ((row & 7) << 4)));
    }
    const uint8_t* wc = wbuf + (i & 1) * 8192 + (wcc * 4) * 1024 + (size_t)lane * 16;
#pragma unroll
    for (int fc = 0; fc < 4; ++fc) bb[fc] = *(const bf16x8*)(wc + fc * 1024);
#pragma unroll
    for (int fr = 0; fr < 4; ++fr)
#pragma unroll
      for (int fc = 0; fc < 4; ++fc)
        acc[fr][fc] = __builtin_amdgcn_mfma_f32_16x16x32_bf16(a[fr], bb[fc], acc[fr][fc], 0, 0, 0);
    __syncthreads();
    if (i == 11) {  // restage X with half-1 channels (xsb free after barrier)
      uint2 raw[9];
#pragma unroll
      for (int it = 0; it < 9; ++it) {
        int u = tid + it * 256;
        if (u < 2080)
          raw[it] = *(const uint2*)(xrowbase + (size_t)(u >> 4) * 256 + 128 + (u & 15) * 8);
      }
#pragma unroll
      for (int it = 0; it < 9; ++it) {
        int u = tid + it * 256;
        if (u < 2080) {
          int row = u >> 4, g8 = u & 15;
          bool valid = (unsigned)(l0 - 1 + row) < (unsigned)NVALID;
          uint4 p = stage8(raw[it], s2, t2, 128 + g8 * 8, valid);
          *(uint4*)(xsb + row * 256 + ((g8 * 16) ^ ((row & 7) << 4))) = p;
        }
      }
      __syncthreads();
    }
  }
  // epilogue
  float ps[4] = {0.f, 0.f, 0.f, 0.f}, pq[4] = {0.f, 0.f, 0.f, 0.f};
#pragma unroll
  for (int fr = 0; fr < 4; ++fr)
#pragma unroll
    for (int fc = 0; fc < 4; ++fc) {
      int col = c0 + fc * 16 + lrow;
#pragma unroll
      for (int rg = 0; rg < 4; ++rg) {
        int r = r0 + fr * 16 + lk * 4 + rg;
        float v = acc[fr][fc][rg];
        xsb[r * 128 + col] = f2fp8(v);
        if (l0 + r < NVALID) {
          ps[fc] += v;
          pq[fc] += v * v;
        }
      }
    }
#pragma unroll
  for (int fc = 0; fc < 4; ++fc) {
    float s = ps[fc], q = pq[fc];
    s += __shfl_xor(s, 16); s += __shfl_xor(s, 32);
    q += __shfl_xor(q, 16); q += __shfl_xor(q, 32);
    if (lk == 0) {
      int col = c0 + fc * 16 + lrow;
      sred[wr][0][col] = s;
      sred[wr][1][col] = q;
    }
  }
  __syncthreads();
  {
    uint8_t* yb = y3 + ((size_t)b * LROWS + (ROW0 + l0)) * 128;
    int row = tid >> 1, q = tid & 1;
    const uint8_t* src = xsb + row * 128 + q * 64;
    uint8_t* dst = yb + (size_t)row * 128 + q * 64;
    uint4 v0 = *(const uint4*)(src);
    uint4 v1 = *(const uint4*)(src + 16);
    uint4 v2 = *(const uint4*)(src + 32);
    uint4 v3 = *(const uint4*)(src + 48);
    *(uint4*)(dst) = v0;
    *(uint4*)(dst + 16) = v1;
    *(uint4*)(dst + 32) = v2;
    *(uint4*)(dst + 48) = v3;
  }
  if (tid < 128) {
    float* pb = partials + ((size_t)b * 33 + blockIdx.x) * 256;
    pb[tid] = sred[0][0][tid] + sred[1][0][tid];
    pb[128 + tid] = sred[0][1][tid] + sred[1][1][tid];
  }
}

// ---------------- feat: BN3+ReLU fused into length-mean partials ----------------
__global__ __launch_bounds__(256) void feat_kernel(const uint8_t* __restrict__ y3,
                                                   const float* __restrict__ s3,
                                                   const float* __restrict__ t3,
                                                   float* __restrict__ fpart) {
  const int b = blockIdx.y, chk = blockIdx.x;
  const int cq = threadIdx.x & 31, lg = threadIdx.x >> 5;
  const uint8_t* base = y3 + ((size_t)b * LROWS + ROW0) * 128;
  float sc[4], sh[4], acc[4] = {0.f, 0.f, 0.f, 0.f};
#pragma unroll
  for (int ci = 0; ci < 4; ++ci) {
    sc[ci] = s3[cq * 4 + ci];
    sh[ci] = t3[cq * 4 + ci];
  }
  int lstart = chk * 513, lend = lstart + 513;
  if (lend > NVALID) lend = NVALID;
  for (int l = lstart + lg; l < lend; l += 8) {
    unsigned u = *(const unsigned*)(base + (size_t)l * 128 + cq * 4);
#pragma unroll
    for (int ci = 0; ci < 4; ++ci)
      acc[ci] += fmaxf(fp82f((u >> (8 * ci)) & 0xffu) * sc[ci] + sh[ci], 0.f);
  }
  __shared__ float red[8][128];
#pragma unroll
  for (int ci = 0; ci < 4; ++ci) red[lg][cq * 4 + ci] = acc[ci];
  __syncthreads();
  if (threadIdx.x < 128) {
    float sum = 0.f;
#pragma unroll
    for (int g = 0; g < 8; ++g) sum += red[g][threadIdx.x];
    fpart[((size_t)chk * 128 + b) * 128 + threadIdx.x] = sum;
  }
}

// ---------------- head: NALU x2 + final linear (fp32) ---------------------------
__global__ __launch_bounds__(128) void head_kernel(const float* __restrict__ fpart,
                                                   const float* __restrict__ W1,
                                                   const float* __restrict__ G1,
                                                   const float* __restrict__ W2,
                                                   const float* __restrict__ G2,
                                                   const float* __restrict__ fw,
                                                   const float* __restrict__ fb,
                                                   float* __restrict__ out) {
  const int b = blockIdx.x, j = threadIdx.x;
  __shared__ float xs[128], lxs[128], h1[128], lh1[128], h2[16];
  float x = 0.f;
#pragma unroll
  for (int chk = 0; chk < 8; ++chk) x += fpart[((size_t)chk * 128 + b) * 128 + j];
  x *= (1.0f / 4097.0f);
  xs[j] = x;
  lxs[j] = logf(fabsf(x) + 1e-10f);
  __syncthreads();
  float a = 0.f, me = 0.f, ga = 0.f;
  for (int i = 0; i < 128; ++i) {
    float w = W1[j * 128 + i];
    a += xs[i] * w;
    me += lxs[i] * w;
    ga += xs[i] * G1[j * 128 + i];
  }
  float g = 1.0f / (1.0f + expf(-ga));
  float h = g * a + (1.0f - g) * expf(me);
  h1[j] = h;
  lh1[j] = logf(fabsf(h) + 1e-10f);
  __syncthreads();
  if (j < 16) {
    float a2 = 0.f, m2 = 0.f, g2 = 0.f;
    for (int i = 0; i < 128; ++i) {
      float w = W2[j * 128 + i];
      a2 += h1[i] * w;
      m2 += lh1[i] * w;
      g2 += h1[i] * G2[j * 128 + i];
    }
    float gg = 1.0f / (1.0f + expf(-g2));
    h2[j] = gg * a2 + (1.0f - gg) * expf(m2);
  }
  __syncthreads();
  if (j == 0) {
    float o = fb[0];
#pragma unroll
    for (int i = 0; i < 16; ++i) o += h2[i] * fw[i];
    out[b] = o;
  }
}

// ---------------- launch --------------------------------------------------------
extern "C" void kernel_launch(void* const* d_in, const int* in_sizes, int n_in,
                              void* d_out, int out_size, void* d_ws, size_t ws_size,
                              hipStream_t stream) {
  (void)in_sizes; (void)n_in; (void)out_size; (void)ws_size;
  const float* inp = (const float*)d_in[0];
  const float* w1  = (const float*)d_in[1];
  const float* g1  = (const float*)d_in[3];
  const float* b1  = (const float*)d_in[4];
  const float* w2  = (const float*)d_in[5];
  const float* g2  = (const float*)d_in[7];
  const float* b2  = (const float*)d_in[8];
  const float* w3  = (const float*)d_in[9];
  const float* g3  = (const float*)d_in[11];
  const float* b3  = (const float*)d_in[12];
  const float* wh1 = (const float*)d_in[13];
  const float* mh1 = (const float*)d_in[14];
  const float* G1  = (const float*)d_in[15];
  const float* wh2 = (const float*)d_in[16];
  const float* mh2 = (const float*)d_in[17];
  const float* G2  = (const float*)d_in[18];
  const float* fw  = (const float*)d_in[19];
  const float* fb  = (const float*)d_in[20];
  float* out = (float*)d_out;

  uint8_t* ws = (uint8_t*)d_ws;
  size_t off = 0;
  auto alloc = [&](size_t n) {
    uint8_t* p = ws + off;
    off += (n + 255) & ~(size_t)255;
    return p;
  };
  uint8_t* y1  = alloc((size_t)128 * LROWS * 128);   // fp8; later aliased as y3
  uint8_t* y2  = alloc((size_t)128 * LROWS * 256);   // fp8
  uint8_t* w2p = alloc((size_t)320 * 1024);
  uint8_t* w3p = alloc((size_t)192 * 1024);
  float* part1 = (float*)alloc((size_t)2176 * 256 * 4);
  float* part2 = (float*)alloc((size_t)4224 * 512 * 4);
  float* part3 = (float*)alloc((size_t)4224 * 256 * 4);
  float* s1 = (float*)alloc(128 * 4); float* t1 = (float*)alloc(128 * 4);
  float* s2 = (float*)alloc(256 * 4); float* t2 = (float*)alloc(256 * 4);
  float* s3 = (float*)alloc(128 * 4); float* t3 = (float*)alloc(128 * 4);
  float* fpart = (float*)alloc((size_t)8 * 128 * 128 * 4);
  float* W1n = (float*)alloc(128 * 128 * 4);
  float* W2n = (float*)alloc(16 * 128 * 4);
  uint8_t* y3 = y1;  // alias: y1 dead once conv2 done

  prepack_w2_kernel<<<640, 256, 0, stream>>>(w2, w2p);
  prepack_w3_kernel<<<384, 256, 0, stream>>>(w3, w3p);
  prep_nalu_kernel<<<72, 256, 0, stream>>>(wh1, mh1, wh2, mh2, W1n, W2n);

  conv1_kernel<<<dim3(17, 128), 256, 0, stream>>>(inp, w1, y1, part1);
  finalize_kernel<<<128, 256, 0, stream>>>(part1, 2176, 128, g1, b1, s1, t1);

  conv2_kernel<<<dim3(33, 2, 128), 256, 0, stream>>>(y1, w2p, s1, t1, y2, part2);
  finalize_kernel<<<256, 256, 0, stream>>>(part2, 4224, 256, g2, b2, s2, t2);

  conv3_kernel<<<dim3(33, 1, 128), 256, 0, stream>>>(y2, w3p, s2, t2, y3, part3);
  finalize_kernel<<<128, 256, 0, stream>>>(part3, 4224, 128, g3, b3, s3, t3);

  feat_kernel<<<dim3(8, 128), 256, 0, stream>>>(y3, s3, t3, fpart);
  head_kernel<<<128, 128, 0, stream>>>(fpart, W1n, G1, W2n, G2, fw, fb, out);
}

// Round 7
// 607.226 us; speedup vs baseline: 2.7197x; 2.3607x over previous
//
#include <hip/hip_runtime.h>
#include <stdint.h>

#define LROWS 4240
#define ROW0 8
#define NVALID 4097

typedef float f32x4 __attribute__((ext_vector_type(4)));
typedef short bf16x8 __attribute__((ext_vector_type(8)));

#define GLOAD_LDS(gaddr, laddr)                                                            \
  __builtin_amdgcn_global_load_lds((const __attribute__((address_space(1))) void*)(gaddr), \
                                   (__attribute__((address_space(3))) void*)(laddr), 16, 0, 0)

__device__ __forceinline__ unsigned short f2bf(float f) {
  unsigned u = __float_as_uint(f);
  u += 0x7fffu + ((u >> 16) & 1u);
  return (unsigned short)(u >> 16);
}
__device__ __forceinline__ float bf2f(unsigned short h) {
  return __uint_as_float(((unsigned)h) << 16);
}
// OCP e4m3fn codec via exponent-shift trick (exact, incl. subnormals, RNE)
__device__ __forceinline__ uint8_t f2fp8(float f) {
  f = fminf(fmaxf(f, -448.f), 448.f);
  unsigned u = __float_as_uint(f * 0x1p-120f);
  unsigned s = (u >> 24) & 0x80u;
  u &= 0x7fffffffu;
  u += 0x7ffffu + ((u >> 20) & 1u);
  return (uint8_t)(s | (u >> 20));
}
__device__ __forceinline__ float fp82f(unsigned b) {
  return __uint_as_float(((b & 0x80u) << 24) | ((b & 0x7fu) << 20)) * 0x1p120f;
}

// decode 8 fp8 + BN + ReLU -> 8 bf16 packed in uint4 (zero if !valid)
// scale/shift preloaded as float4 pairs (per-thread channel group is fixed)
__device__ __forceinline__ uint4 stage8v(uint2 raw, float4 scA, float4 scB, float4 shA,
                                         float4 shB, bool valid) {
  float sc[8] = {scA.x, scA.y, scA.z, scA.w, scB.x, scB.y, scB.z, scB.w};
  float sh[8] = {shA.x, shA.y, shA.z, shA.w, shB.x, shB.y, shB.z, shB.w};
  unsigned short o[8];
#pragma unroll
  for (int j = 0; j < 8; ++j) {
    float f = 0.f;
    if (valid) {
      unsigned byte = ((j < 4 ? raw.x : raw.y) >> (8 * (j & 3))) & 0xffu;
      f = fmaxf(fp82f(byte) * sc[j] + sh[j], 0.f);
    }
    o[j] = f2bf(f);
  }
  return make_uint4((unsigned)o[0] | ((unsigned)o[1] << 16),
                    (unsigned)o[2] | ((unsigned)o[3] << 16),
                    (unsigned)o[4] | ((unsigned)o[5] << 16),
                    (unsigned)o[6] | ((unsigned)o[7] << 16));
}

// ---------------- weight prepack: per-(K-step, colgroup) 1KB fragment blobs ----
__global__ void prepack_w2_kernel(const float* __restrict__ w2, uint8_t* __restrict__ wp) {
  int i = blockIdx.x * 256 + threadIdx.x;
  if (i >= 163840) return;
  int t = i % 5, oc = i / 5;
  int cin = oc & 127, o = oc >> 7;
  int step = t * 4 + (cin >> 5);
  int og = o >> 4;
  int lane = ((cin >> 3) & 3) * 16 + (o & 15);
  int j = cin & 7;
  *(unsigned short*)(wp + ((size_t)(step * 16 + og) << 10) + lane * 16 + j * 2) = f2bf(w2[i]);
}
__global__ void prepack_w3_kernel(const float* __restrict__ w3, uint8_t* __restrict__ wp) {
  int i = blockIdx.x * 256 + threadIdx.x;
  if (i >= 98304) return;
  int t = i % 3, oc = i / 3;
  int cin = oc & 255, o = oc >> 8;
  int step = t * 8 + (cin >> 5);
  int og = o >> 4;
  int lane = ((cin >> 3) & 3) * 16 + (o & 15);
  int j = cin & 7;
  *(unsigned short*)(wp + ((size_t)(step * 8 + og) << 10) + lane * 16 + j * 2) = f2bf(w3[i]);
}

__global__ void prep_nalu_kernel(const float* __restrict__ wh1, const float* __restrict__ mh1,
                                 const float* __restrict__ wh2, const float* __restrict__ mh2,
                                 float* __restrict__ W1, float* __restrict__ W2) {
  int i = blockIdx.x * 256 + threadIdx.x;
  if (i < 16384) {
    W1[i] = tanhf(wh1[i]) * (1.0f / (1.0f + expf(-mh1[i])));
  } else if (i < 18432) {
    int k = i - 16384;
    W2[k] = tanhf(wh2[k]) * (1.0f / (1.0f + expf(-mh2[k])));
  }
}

// ---------------- conv1: C_in=1, k=8 fp32 vector -> y1 fp8 + stats --------------
__global__ __launch_bounds__(256) void conv1_kernel(const float* __restrict__ inp,
                                                    const float* __restrict__ w1,
                                                    uint8_t* __restrict__ y1,
                                                    float* __restrict__ partials) {
  __shared__ float xsh[272];
  __shared__ float reds[2][8][128];
  const int tid = threadIdx.x;
  const int b = blockIdx.y;
  const int l0 = blockIdx.x * 256;
  const float* xb = inp + (size_t)b * 4096;
  for (int j = tid; j < 263; j += 256) {
    int li = l0 - 4 + j;
    xsh[j] = ((unsigned)li < 4096u) ? xb[li] : 0.f;
  }
  __syncthreads();
  const int cg = tid & 31, lsub = tid >> 5;
  float w[4][8];
#pragma unroll
  for (int ci = 0; ci < 4; ++ci)
#pragma unroll
    for (int t = 0; t < 8; ++t) w[ci][t] = w1[(cg * 4 + ci) * 8 + t];
  float s[4] = {0.f, 0.f, 0.f, 0.f}, q[4] = {0.f, 0.f, 0.f, 0.f};
  uint8_t* yb = y1 + ((size_t)b * LROWS + (ROW0 + l0)) * 128;
  for (int li = lsub; li < 256; li += 8) {
    if (l0 + li >= NVALID) break;
    unsigned pk = 0;
#pragma unroll
    for (int ci = 0; ci < 4; ++ci) {
      float a = 0.f;
#pragma unroll
      for (int t = 0; t < 8; ++t) a += xsh[li + t] * w[ci][t];
      s[ci] += a;
      q[ci] += a * a;
      pk |= (unsigned)f2fp8(a) << (8 * ci);
    }
    *(unsigned*)(yb + (size_t)li * 128 + cg * 4) = pk;
  }
#pragma unroll
  for (int ci = 0; ci < 4; ++ci) {
    reds[0][lsub][cg * 4 + ci] = s[ci];
    reds[1][lsub][cg * 4 + ci] = q[ci];
  }
  __syncthreads();
  if (tid < 128) {
    float ss = 0.f, qq = 0.f;
#pragma unroll
    for (int g = 0; g < 8; ++g) {
      ss += reds[0][g][tid];
      qq += reds[1][g][tid];
    }
    float* pb = partials + ((size_t)b * 17 + blockIdx.x) * 256;
    pb[tid] = ss;
    pb[128 + tid] = qq;
  }
}

// ---------------- BN finalize ---------------------------------------------------
__global__ __launch_bounds__(256) void finalize_kernel(const float* __restrict__ partials,
                                                       int nblk, int C,
                                                       const float* __restrict__ gamma,
                                                       const float* __restrict__ beta,
                                                       float* __restrict__ scale,
                                                       float* __restrict__ shift) {
  int c = blockIdx.x;
  float s = 0.f, q = 0.f;
  for (int i = threadIdx.x; i < nblk; i += 256) {
    const float* p = partials + (size_t)i * 2 * C;
    s += p[c];
    q += p[C + c];
  }
  __shared__ float rs[256], rq[256];
  rs[threadIdx.x] = s;
  rq[threadIdx.x] = q;
  __syncthreads();
  for (int st = 128; st > 0; st >>= 1) {
    if (threadIdx.x < st) {
      rs[threadIdx.x] += rs[threadIdx.x + st];
      rq[threadIdx.x] += rq[threadIdx.x + st];
    }
    __syncthreads();
  }
  if (threadIdx.x == 0) {
    const float N = 128.0f * 4097.0f;
    float mean = rs[0] / N;
    float var = rq[0] / N - mean * mean;
    float sc = gamma[c] * rsqrtf(var + 1e-5f);
    scale[c] = sc;
    shift[c] = beta[c] - mean * sc;
  }
}

// ---------------- conv2: counted-vmcnt pipeline (T3+T4+T5) ----------------------
// 256 thr, 4 waves (2x2), wave 64x64; tile 128 rows x 128 cout (h2 = cout half).
// W: 3x8KB LDS ring via global_load_lds, depth-2 prefetch, s_waitcnt vmcnt(2).
__global__ __launch_bounds__(256, 2) void conv2_kernel(const uint8_t* __restrict__ y1,
                                                       const uint8_t* __restrict__ wp,
                                                       const float* __restrict__ s1,
                                                       const float* __restrict__ t1,
                                                       uint8_t* __restrict__ y2,
                                                       float* __restrict__ partials) {
  __shared__ uint4 xs4[2112];  // 132 rows x 256B bf16, XOR-swizzled
  __shared__ uint4 wb4[1536];  // 3 x 8KB weight ring
  uint8_t* xsb = (uint8_t*)xs4;
  uint8_t* wbuf = (uint8_t*)wb4;
  const int tid = threadIdx.x;
  const int b = blockIdx.z;
  const int h2 = blockIdx.y;
  const int l0 = blockIdx.x * 128;
  const uint8_t* wph = wp + (size_t)h2 * 8192;
  // issue W chunks 0,1 async
  GLOAD_LDS(wph + tid * 16, wbuf + tid * 16);
  GLOAD_LDS(wph + 4096 + tid * 16, wbuf + 4096 + tid * 16);
  GLOAD_LDS(wph + 16384 + tid * 16, wbuf + 8192 + tid * 16);
  GLOAD_LDS(wph + 16384 + 4096 + tid * 16, wbuf + 8192 + 4096 + tid * 16);
  // reg-stage X (fp8 -> BN+ReLU -> bf16); per-thread channel group fixed
  {
    const int c0s = (tid & 15) * 8;
    float4 scA = *(const float4*)(s1 + c0s), scB = *(const float4*)(s1 + c0s + 4);
    float4 shA = *(const float4*)(t1 + c0s), shB = *(const float4*)(t1 + c0s + 4);
    const uint8_t* xrow = y1 + ((size_t)b * LROWS + (ROW0 + l0 - 2)) * 128;
    uint2 raw[9];
#pragma unroll
    for (int it = 0; it < 9; ++it) {
      int u = tid + it * 256;
      if (u < 2112) raw[it] = *(const uint2*)(xrow + (size_t)(u >> 4) * 128 + (u & 15) * 8);
    }
#pragma unroll
    for (int it = 0; it < 9; ++it) {
      int u = tid + it * 256;
      if (u < 2112) {
        int row = u >> 4, g8 = u & 15;
        bool valid = (unsigned)(l0 - 2 + row) < (unsigned)NVALID;
        uint4 p = stage8v(raw[it], scA, scB, shA, shB, valid);
        *(uint4*)(xsb + row * 256 + ((g8 * 16) ^ ((row & 7) << 4))) = p;
      }
    }
  }
  __syncthreads();
  const int lane = tid & 63, wid = tid >> 6;
  const int wr = wid >> 1, wcc = wid & 1;
  const int lrow = lane & 15, lk = lane >> 4;
  const int r0 = wr * 64, c0 = wcc * 64;
  f32x4 acc[4][4] = {};
#pragma unroll
  for (int s = 0; s < 20; ++s) {
    if (s < 18) {  // depth-2 prefetch into ring slot (s+2)%3
      const uint8_t* src = wph + (size_t)(s + 2) * 16384;
      uint8_t* dst = wbuf + ((s + 2) % 3) * 8192;
      GLOAD_LDS(src + tid * 16, dst + tid * 16);
      GLOAD_LDS(src + 4096 + tid * 16, dst + 4096 + tid * 16);
    }
    const int t = s >> 2, kk = s & 3;
    bf16x8 a[4], bb[4];
#pragma unroll
    for (int fr = 0; fr < 4; ++fr) {
      int row = r0 + fr * 16 + lrow + t;
      a[fr] = *(const bf16x8*)(xsb + row * 256 + ((kk * 64 + lk * 16) ^ ((row & 7) << 4)));
    }
    const uint8_t* wc = wbuf + (s % 3) * 8192 + (wcc * 4) * 1024 + (size_t)lane * 16;
#pragma unroll
    for (int fc = 0; fc < 4; ++fc) bb[fc] = *(const bf16x8*)(wc + fc * 1024);
    __builtin_amdgcn_s_setprio(1);
#pragma unroll
    for (int fr = 0; fr < 4; ++fr)
#pragma unroll
      for (int fc = 0; fc < 4; ++fc)
        acc[fr][fc] = __builtin_amdgcn_mfma_f32_16x16x32_bf16(a[fr], bb[fc], acc[fr][fc], 0, 0, 0);
    __builtin_amdgcn_s_setprio(0);
    if (s < 18) {
      asm volatile("s_waitcnt vmcnt(2)" ::: "memory");  // next chunk landed; s+2 in flight
    } else {
      asm volatile("s_waitcnt vmcnt(0)" ::: "memory");
    }
    __builtin_amdgcn_s_barrier();
  }
  // epilogue: fp8 into dead X LDS + stats (sred reuses dead W ring)
  float* sred = (float*)wb4;  // [4][128]
  float ps[4] = {0.f, 0.f, 0.f, 0.f}, pq[4] = {0.f, 0.f, 0.f, 0.f};
#pragma unroll
  for (int fr = 0; fr < 4; ++fr)
#pragma unroll
    for (int fc = 0; fc < 4; ++fc) {
      int col = c0 + fc * 16 + lrow;
#pragma unroll
      for (int rg = 0; rg < 4; ++rg) {
        int r = r0 + fr * 16 + lk * 4 + rg;
        float v = acc[fr][fc][rg];
        xsb[r * 128 + col] = f2fp8(v);
        if (l0 + r < NVALID) {
          ps[fc] += v;
          pq[fc] += v * v;
        }
      }
    }
#pragma unroll
  for (int fc = 0; fc < 4; ++fc) {
    float s = ps[fc], q = pq[fc];
    s += __shfl_xor(s, 16); s += __shfl_xor(s, 32);
    q += __shfl_xor(q, 16); q += __shfl_xor(q, 32);
    if (lk == 0) {
      int col = c0 + fc * 16 + lrow;
      sred[(wr * 2 + 0) * 128 + col] = s;
      sred[(wr * 2 + 1) * 128 + col] = q;
    }
  }
  __syncthreads();
  {
    uint8_t* yb = y2 + ((size_t)b * LROWS + (ROW0 + l0)) * 256 + h2 * 128;
    int row = tid >> 1, q = tid & 1;
    const uint8_t* src = xsb + row * 128 + q * 64;
    uint8_t* dst = yb + (size_t)row * 256 + q * 64;
    uint4 v0 = *(const uint4*)(src);
    uint4 v1 = *(const uint4*)(src + 16);
    uint4 v2 = *(const uint4*)(src + 32);
    uint4 v3 = *(const uint4*)(src + 48);
    *(uint4*)(dst) = v0;
    *(uint4*)(dst + 16) = v1;
    *(uint4*)(dst + 32) = v2;
    *(uint4*)(dst + 48) = v3;
  }
  if (tid < 128) {
    float* pb = partials + ((size_t)b * 33 + blockIdx.x) * 512;
    pb[h2 * 128 + tid] = sred[0 * 128 + tid] + sred[2 * 128 + tid];
    pb[256 + h2 * 128 + tid] = sred[1 * 128 + tid] + sred[3 * 128 + tid];
  }
}

// ---------------- conv3: counted-vmcnt pipeline, 2 channel-halves ---------------
__global__ __launch_bounds__(256, 2) void conv3_kernel(const uint8_t* __restrict__ y2,
                                                       const uint8_t* __restrict__ wp,
                                                       const float* __restrict__ s2,
                                                       const float* __restrict__ t2,
                                                       uint8_t* __restrict__ y3,
                                                       float* __restrict__ partials) {
  __shared__ uint4 xs4[2080];  // 130 rows x 256B (one 128-ch half), swizzled
  __shared__ uint4 wb4[1536];  // 3 x 8KB ring
  uint8_t* xsb = (uint8_t*)xs4;
  uint8_t* wbuf = (uint8_t*)wb4;
  const int tid = threadIdx.x;
  const int b = blockIdx.z;
  const int l0 = blockIdx.x * 128;
  const uint8_t* xrowbase = y2 + ((size_t)b * LROWS + (ROW0 + l0 - 1)) * 256;
  const int c0s = (tid & 15) * 8;
  // W blob base for chunk n: hn=n/12, rn=n%12 -> ((rn>>2)*8 + hn*4 + (rn&3)) * 8KB
#define W3BASE(n) ((size_t)((((n) % 12) >> 2) * 8 + ((n) / 12) * 4 + ((n) & 3)) * 8192)
  // issue W chunks 0,1
  GLOAD_LDS(wp + W3BASE(0) + tid * 16, wbuf + tid * 16);
  GLOAD_LDS(wp + W3BASE(0) + 4096 + tid * 16, wbuf + 4096 + tid * 16);
  GLOAD_LDS(wp + W3BASE(1) + tid * 16, wbuf + 8192 + tid * 16);
  GLOAD_LDS(wp + W3BASE(1) + 4096 + tid * 16, wbuf + 8192 + 4096 + tid * 16);
  // stage X half-0
  {
    float4 scA = *(const float4*)(s2 + c0s), scB = *(const float4*)(s2 + c0s + 4);
    float4 shA = *(const float4*)(t2 + c0s), shB = *(const float4*)(t2 + c0s + 4);
    uint2 raw[9];
#pragma unroll
    for (int it = 0; it < 9; ++it) {
      int u = tid + it * 256;
      if (u < 2080) raw[it] = *(const uint2*)(xrowbase + (size_t)(u >> 4) * 256 + (u & 15) * 8);
    }
#pragma unroll
    for (int it = 0; it < 9; ++it) {
      int u = tid + it * 256;
      if (u < 2080) {
        int row = u >> 4, g8 = u & 15;
        bool valid = (unsigned)(l0 - 1 + row) < (unsigned)NVALID;
        uint4 p = stage8v(raw[it], scA, scB, shA, shB, valid);
        *(uint4*)(xsb + row * 256 + ((g8 * 16) ^ ((row & 7) << 4))) = p;
      }
    }
  }
  __syncthreads();
  const int lane = tid & 63, wid = tid >> 6;
  const int wr = wid >> 1, wcc = wid & 1;
  const int lrow = lane & 15, lk = lane >> 4;
  const int r0 = wr * 64, c0 = wcc * 64;
  f32x4 acc[4][4] = {};
#define C3STEP(S)                                                                       \
  {                                                                                     \
    if ((S) < 22) {                                                                     \
      const uint8_t* src = wp + W3BASE((S) + 2);                                        \
      uint8_t* dst = wbuf + (((S) + 2) % 3) * 8192;                                     \
      GLOAD_LDS(src + tid * 16, dst + tid * 16);                                        \
      GLOAD_LDS(src + 4096 + tid * 16, dst + 4096 + tid * 16);                          \
    }                                                                                   \
    const int t_ = ((S) % 12) >> 2, kq_ = (S) & 3;                                      \
    bf16x8 a[4], bb[4];                                                                 \
    _Pragma("unroll") for (int fr = 0; fr < 4; ++fr) {                                  \
      int row = r0 + fr * 16 + lrow + t_;                                               \
      a[fr] = *(const bf16x8*)(xsb + row * 256 +                                        \
                               ((kq_ * 64 + lk * 16) ^ ((row & 7) << 4)));              \
    }                                                                                   \
    const uint8_t* wc = wbuf + ((S) % 3) * 8192 + (wcc * 4) * 1024 + (size_t)lane * 16; \
    _Pragma("unroll") for (int fc = 0; fc < 4; ++fc) bb[fc] = *(const bf16x8*)(wc + fc * 1024); \
    __builtin_amdgcn_s_setprio(1);                                                      \
    _Pragma("unroll") for (int fr = 0; fr < 4; ++fr)                                    \
        _Pragma("unroll") for (int fc = 0; fc < 4; ++fc)                                \
            acc[fr][fc] =                                                               \
                __builtin_amdgcn_mfma_f32_16x16x32_bf16(a[fr], bb[fc], acc[fr][fc], 0, 0, 0); \
    __builtin_amdgcn_s_setprio(0);                                                      \
    if ((S) < 22) {                                                                     \
      asm volatile("s_waitcnt vmcnt(2)" ::: "memory");                                  \
    } else {                                                                            \
      asm volatile("s_waitcnt vmcnt(0)" ::: "memory");                                  \
    }                                                                                   \
    __builtin_amdgcn_s_barrier();                                                       \
  }
#pragma unroll
  for (int s = 0; s < 12; ++s) C3STEP(s);
  // restage X with half-1 channels (xsb free after chunk-11 barrier)
  {
    float4 scA = *(const float4*)(s2 + 128 + c0s), scB = *(const float4*)(s2 + 128 + c0s + 4);
    float4 shA = *(const float4*)(t2 + 128 + c0s), shB = *(const float4*)(t2 + 128 + c0s + 4);
    uint2 raw[9];
#pragma unroll
    for (int it = 0; it < 9; ++it) {
      int u = tid + it * 256;
      if (u < 2080)
        raw[it] = *(const uint2*)(xrowbase + (size_t)(u >> 4) * 256 + 128 + (u & 15) * 8);
    }
#pragma unroll
    for (int it = 0; it < 9; ++it) {
      int u = tid + it * 256;
      if (u < 2080) {
        int row = u >> 4, g8 = u & 15;
        bool valid = (unsigned)(l0 - 1 + row) < (unsigned)NVALID;
        uint4 p = stage8v(raw[it], scA, scB, shA, shB, valid);
        *(uint4*)(xsb + row * 256 + ((g8 * 16) ^ ((row & 7) << 4))) = p;
      }
    }
  }
  __syncthreads();
#pragma unroll
  for (int s = 12; s < 24; ++s) C3STEP(s);
  // epilogue
  float* sred = (float*)wb4;  // [4][128]
  float ps[4] = {0.f, 0.f, 0.f, 0.f}, pq[4] = {0.f, 0.f, 0.f, 0.f};
#pragma unroll
  for (int fr = 0; fr < 4; ++fr)
#pragma unroll
    for (int fc = 0; fc < 4; ++fc) {
      int col = c0 + fc * 16 + lrow;
#pragma unroll
      for (int rg = 0; rg < 4; ++rg) {
        int r = r0 + fr * 16 + lk * 4 + rg;
        float v = acc[fr][fc][rg];
        xsb[r * 128 + col] = f2fp8(v);
        if (l0 + r < NVALID) {
          ps[fc] += v;
          pq[fc] += v * v;
        }
      }
    }
#pragma unroll
  for (int fc = 0; fc < 4; ++fc) {
    float s = ps[fc], q = pq[fc];
    s += __shfl_xor(s, 16); s += __shfl_xor(s, 32);
    q += __shfl_xor(q, 16); q += __shfl_xor(q, 32);
    if (lk == 0) {
      int col = c0 + fc * 16 + lrow;
      sred[(wr * 2 + 0) * 128 + col] = s;
      sred[(wr * 2 + 1) * 128 + col] = q;
    }
  }
  __syncthreads();
  {
    uint8_t* yb = y3 + ((size_t)b * LROWS + (ROW0 + l0)) * 128;
    int row = tid >> 1, q = tid & 1;
    const uint8_t* src = xsb + row * 128 + q * 64;
    uint8_t* dst = yb + (size_t)row * 128 + q * 64;
    uint4 v0 = *(const uint4*)(src);
    uint4 v1 = *(const uint4*)(src + 16);
    uint4 v2 = *(const uint4*)(src + 32);
    uint4 v3 = *(const uint4*)(src + 48);
    *(uint4*)(dst) = v0;
    *(uint4*)(dst + 16) = v1;
    *(uint4*)(dst + 32) = v2;
    *(uint4*)(dst + 48) = v3;
  }
  if (tid < 128) {
    float* pb = partials + ((size_t)b * 33 + blockIdx.x) * 256;
    pb[tid] = sred[0 * 128 + tid] + sred[2 * 128 + tid];
    pb[128 + tid] = sred[1 * 128 + tid] + sred[3 * 128 + tid];
  }
}

// ---------------- feat: BN3+ReLU fused into length-mean partials ----------------
__global__ __launch_bounds__(256) void feat_kernel(const uint8_t* __restrict__ y3,
                                                   const float* __restrict__ s3,
                                                   const float* __restrict__ t3,
                                                   float* __restrict__ fpart) {
  const int b = blockIdx.y, chk = blockIdx.x;
  const int cq = threadIdx.x & 31, lg = threadIdx.x >> 5;
  const uint8_t* base = y3 + ((size_t)b * LROWS + ROW0) * 128;
  float sc[4], sh[4], acc[4] = {0.f, 0.f, 0.f, 0.f};
#pragma unroll
  for (int ci = 0; ci < 4; ++ci) {
    sc[ci] = s3[cq * 4 + ci];
    sh[ci] = t3[cq * 4 + ci];
  }
  int lstart = chk * 513, lend = lstart + 513;
  if (lend > NVALID) lend = NVALID;
  for (int l = lstart + lg; l < lend; l += 8) {
    unsigned u = *(const unsigned*)(base + (size_t)l * 128 + cq * 4);
#pragma unroll
    for (int ci = 0; ci < 4; ++ci)
      acc[ci] += fmaxf(fp82f((u >> (8 * ci)) & 0xffu) * sc[ci] + sh[ci], 0.f);
  }
  __shared__ float red[8][128];
#pragma unroll
  for (int ci = 0; ci < 4; ++ci) red[lg][cq * 4 + ci] = acc[ci];
  __syncthreads();
  if (threadIdx.x < 128) {
    float sum = 0.f;
#pragma unroll
    for (int g = 0; g < 8; ++g) sum += red[g][threadIdx.x];
    fpart[((size_t)chk * 128 + b) * 128 + threadIdx.x] = sum;
  }
}

// ---------------- head: NALU x2 + final linear (fp32) ---------------------------
__global__ __launch_bounds__(128) void head_kernel(const float* __restrict__ fpart,
                                                   const float* __restrict__ W1,
                                                   const float* __restrict__ G1,
                                                   const float* __restrict__ W2,
                                                   const float* __restrict__ G2,
                                                   const float* __restrict__ fw,
                                                   const float* __restrict__ fb,
                                                   float* __restrict__ out) {
  const int b = blockIdx.x, j = threadIdx.x;
  __shared__ float xs[128], lxs[128], h1[128], lh1[128], h2[16];
  float x = 0.f;
#pragma unroll
  for (int chk = 0; chk < 8; ++chk) x += fpart[((size_t)chk * 128 + b) * 128 + j];
  x *= (1.0f / 4097.0f);
  xs[j] = x;
  lxs[j] = logf(fabsf(x) + 1e-10f);
  __syncthreads();
  float a = 0.f, me = 0.f, ga = 0.f;
  for (int i = 0; i < 128; ++i) {
    float w = W1[j * 128 + i];
    a += xs[i] * w;
    me += lxs[i] * w;
    ga += xs[i] * G1[j * 128 + i];
  }
  float g = 1.0f / (1.0f + expf(-ga));
  float h = g * a + (1.0f - g) * expf(me);
  h1[j] = h;
  lh1[j] = logf(fabsf(h) + 1e-10f);
  __syncthreads();
  if (j < 16) {
    float a2 = 0.f, m2 = 0.f, g2 = 0.f;
    for (int i = 0; i < 128; ++i) {
      float w = W2[j * 128 + i];
      a2 += h1[i] * w;
      m2 += lh1[i] * w;
      g2 += h1[i] * G2[j * 128 + i];
    }
    float gg = 1.0f / (1.0f + expf(-g2));
    h2[j] = gg * a2 + (1.0f - gg) * expf(m2);
  }
  __syncthreads();
  if (j == 0) {
    float o = fb[0];
#pragma unroll
    for (int i = 0; i < 16; ++i) o += h2[i] * fw[i];
    out[b] = o;
  }
}

// ---------------- launch --------------------------------------------------------
extern "C" void kernel_launch(void* const* d_in, const int* in_sizes, int n_in,
                              void* d_out, int out_size, void* d_ws, size_t ws_size,
                              hipStream_t stream) {
  (void)in_sizes; (void)n_in; (void)out_size; (void)ws_size;
  const float* inp = (const float*)d_in[0];
  const float* w1  = (const float*)d_in[1];
  const float* g1  = (const float*)d_in[3];
  const float* b1  = (const float*)d_in[4];
  const float* w2  = (const float*)d_in[5];
  const float* g2  = (const float*)d_in[7];
  const float* b2  = (const float*)d_in[8];
  const float* w3  = (const float*)d_in[9];
  const float* g3  = (const float*)d_in[11];
  const float* b3  = (const float*)d_in[12];
  const float* wh1 = (const float*)d_in[13];
  const float* mh1 = (const float*)d_in[14];
  const float* G1  = (const float*)d_in[15];
  const float* wh2 = (const float*)d_in[16];
  const float* mh2 = (const float*)d_in[17];
  const float* G2  = (const float*)d_in[18];
  const float* fw  = (const float*)d_in[19];
  const float* fb  = (const float*)d_in[20];
  float* out = (float*)d_out;

  uint8_t* ws = (uint8_t*)d_ws;
  size_t off = 0;
  auto alloc = [&](size_t n) {
    uint8_t* p = ws + off;
    off += (n + 255) & ~(size_t)255;
    return p;
  };
  uint8_t* y1  = alloc((size_t)128 * LROWS * 128);   // fp8; later aliased as y3
  uint8_t* y2  = alloc((size_t)128 * LROWS * 256);   // fp8
  uint8_t* w2p = alloc((size_t)320 * 1024);
  uint8_t* w3p = alloc((size_t)192 * 1024);
  float* part1 = (float*)alloc((size_t)2176 * 256 * 4);
  float* part2 = (float*)alloc((size_t)4224 * 512 * 4);
  float* part3 = (float*)alloc((size_t)4224 * 256 * 4);
  float* s1 = (float*)alloc(128 * 4); float* t1 = (float*)alloc(128 * 4);
  float* s2 = (float*)alloc(256 * 4); float* t2 = (float*)alloc(256 * 4);
  float* s3 = (float*)alloc(128 * 4); float* t3 = (float*)alloc(128 * 4);
  float* fpart = (float*)alloc((size_t)8 * 128 * 128 * 4);
  float* W1n = (float*)alloc(128 * 128 * 4);
  float* W2n = (float*)alloc(16 * 128 * 4);
  uint8_t* y3 = y1;  // alias: y1 dead once conv2 done

  prepack_w2_kernel<<<640, 256, 0, stream>>>(w2, w2p);
  prepack_w3_kernel<<<384, 256, 0, stream>>>(w3, w3p);
  prep_nalu_kernel<<<72, 256, 0, stream>>>(wh1, mh1, wh2, mh2, W1n, W2n);

  conv1_kernel<<<dim3(17, 128), 256, 0, stream>>>(inp, w1, y1, part1);
  finalize_kernel<<<128, 256, 0, stream>>>(part1, 2176, 128, g1, b1, s1, t1);

  conv2_kernel<<<dim3(33, 2, 128), 256, 0, stream>>>(y1, w2p, s1, t1, y2, part2);
  finalize_kernel<<<256, 256, 0, stream>>>(part2, 4224, 256, g2, b2, s2, t2);

  conv3_kernel<<<dim3(33, 1, 128), 256, 0, stream>>>(y2, w3p, s2, t2, y3, part3);
  finalize_kernel<<<128, 256, 0, stream>>>(part3, 4224, 128, g3, b3, s3, t3);

  feat_kernel<<<dim3(8, 128), 256, 0, stream>>>(y3, s3, t3, fpart);
  head_kernel<<<128, 128, 0, stream>>>(fpart, W1n, G1, W2n, G2, fw, fb, out);
}

// Round 9
// 542.637 us; speedup vs baseline: 3.0434x; 1.1190x over previous
//
#include <hip/hip_runtime.h>
#include <stdint.h>

#define LROWS 4240
#define ROW0 8
#define NVALID 4097

typedef float f32x4 __attribute__((ext_vector_type(4)));
typedef float f32x2 __attribute__((ext_vector_type(2)));
typedef short bf16x8 __attribute__((ext_vector_type(8)));

#define GLOAD_LDS(gaddr, laddr)                                                            \
  __builtin_amdgcn_global_load_lds((const __attribute__((address_space(1))) void*)(gaddr), \
                                   (__attribute__((address_space(3))) void*)(laddr), 16, 0, 0)

__device__ __forceinline__ unsigned short f2bf(float f) {
  unsigned u = __float_as_uint(f);
  u += 0x7fffu + ((u >> 16) & 1u);
  return (unsigned short)(u >> 16);
}

// decode 8 fp8 (uint2) + BN + ReLU -> 8 bf16 packed in uint4, via HW converters
__device__ __forceinline__ uint4 stage8c(uint2 raw, const float* __restrict__ sc8,
                                         const float* __restrict__ sh8, bool valid) {
  f32x2 d[4];
  d[0] = __builtin_amdgcn_cvt_pk_f32_fp8(raw.x, false);
  d[1] = __builtin_amdgcn_cvt_pk_f32_fp8(raw.x, true);
  d[2] = __builtin_amdgcn_cvt_pk_f32_fp8(raw.y, false);
  d[3] = __builtin_amdgcn_cvt_pk_f32_fp8(raw.y, true);
  uint4 outv;
  unsigned* o = (unsigned*)&outv;
#pragma unroll
  for (int p = 0; p < 4; ++p) {
    float lo = valid ? fmaxf(fmaf(d[p].x, sc8[2 * p], sh8[2 * p]), 0.f) : 0.f;
    float hi = valid ? fmaxf(fmaf(d[p].y, sc8[2 * p + 1], sh8[2 * p + 1]), 0.f) : 0.f;
    unsigned r;
    asm("v_cvt_pk_bf16_f32 %0, %1, %2" : "=v"(r) : "v"(lo), "v"(hi));
    o[p] = r;
  }
  return outv;
}

// ---------------- weight prepack: per-(K-step, colgroup) 1KB fragment blobs ----
__global__ void prepack_w2_kernel(const float* __restrict__ w2, uint8_t* __restrict__ wp) {
  int i = blockIdx.x * 256 + threadIdx.x;
  if (i >= 163840) return;
  int t = i % 5, oc = i / 5;
  int cin = oc & 127, o = oc >> 7;
  int step = t * 4 + (cin >> 5);
  int og = o >> 4;
  int lane = ((cin >> 3) & 3) * 16 + (o & 15);
  int j = cin & 7;
  *(unsigned short*)(wp + ((size_t)(step * 16 + og) << 10) + lane * 16 + j * 2) = f2bf(w2[i]);
}
__global__ void prepack_w3_kernel(const float* __restrict__ w3, uint8_t* __restrict__ wp) {
  int i = blockIdx.x * 256 + threadIdx.x;
  if (i >= 98304) return;
  int t = i % 3, oc = i / 3;
  int cin = oc & 255, o = oc >> 8;
  int step = t * 8 + (cin >> 5);
  int og = o >> 4;
  int lane = ((cin >> 3) & 3) * 16 + (o & 15);
  int j = cin & 7;
  *(unsigned short*)(wp + ((size_t)(step * 8 + og) << 10) + lane * 16 + j * 2) = f2bf(w3[i]);
}

__global__ void prep_nalu_kernel(const float* __restrict__ wh1, const float* __restrict__ mh1,
                                 const float* __restrict__ wh2, const float* __restrict__ mh2,
                                 float* __restrict__ W1, float* __restrict__ W2) {
  int i = blockIdx.x * 256 + threadIdx.x;
  if (i < 16384) {
    W1[i] = tanhf(wh1[i]) * (1.0f / (1.0f + expf(-mh1[i])));
  } else if (i < 18432) {
    int k = i - 16384;
    W2[k] = tanhf(wh2[k]) * (1.0f / (1.0f + expf(-mh2[k])));
  }
}

// ---------------- conv1: C_in=1, k=8 fp32 vector -> y1 fp8 + stats --------------
__global__ __launch_bounds__(256) void conv1_kernel(const float* __restrict__ inp,
                                                    const float* __restrict__ w1,
                                                    uint8_t* __restrict__ y1,
                                                    float* __restrict__ partials) {
  __shared__ float xsh[272];
  __shared__ float reds[2][8][128];
  const int tid = threadIdx.x;
  const int b = blockIdx.y;
  const int l0 = blockIdx.x * 256;
  const float* xb = inp + (size_t)b * 4096;
  for (int j = tid; j < 263; j += 256) {
    int li = l0 - 4 + j;
    xsh[j] = ((unsigned)li < 4096u) ? xb[li] : 0.f;
  }
  __syncthreads();
  const int cg = tid & 31, lsub = tid >> 5;
  float w[4][8];
#pragma unroll
  for (int ci = 0; ci < 4; ++ci)
#pragma unroll
    for (int t = 0; t < 8; ++t) w[ci][t] = w1[(cg * 4 + ci) * 8 + t];
  float s[4] = {0.f, 0.f, 0.f, 0.f}, q[4] = {0.f, 0.f, 0.f, 0.f};
  uint8_t* yb = y1 + ((size_t)b * LROWS + (ROW0 + l0)) * 128;
  for (int li = lsub; li < 256; li += 8) {
    if (l0 + li >= NVALID) break;
    float av[4];
#pragma unroll
    for (int ci = 0; ci < 4; ++ci) {
      float a = 0.f;
#pragma unroll
      for (int t = 0; t < 8; ++t) a += xsh[li + t] * w[ci][t];
      s[ci] += a;
      q[ci] += a * a;
      av[ci] = a;
    }
    unsigned pk = __builtin_amdgcn_cvt_pk_fp8_f32(av[0], av[1], 0, false);
    pk = __builtin_amdgcn_cvt_pk_fp8_f32(av[2], av[3], pk, true);
    *(unsigned*)(yb + (size_t)li * 128 + cg * 4) = pk;
  }
#pragma unroll
  for (int ci = 0; ci < 4; ++ci) {
    reds[0][lsub][cg * 4 + ci] = s[ci];
    reds[1][lsub][cg * 4 + ci] = q[ci];
  }
  __syncthreads();
  if (tid < 128) {
    float ss = 0.f, qq = 0.f;
#pragma unroll
    for (int g = 0; g < 8; ++g) {
      ss += reds[0][g][tid];
      qq += reds[1][g][tid];
    }
    float* pb = partials + ((size_t)b * 17 + blockIdx.x) * 256;
    pb[tid] = ss;
    pb[128 + tid] = qq;
  }
}

// ---------------- BN finalize ---------------------------------------------------
__global__ __launch_bounds__(256) void finalize_kernel(const float* __restrict__ partials,
                                                       int nblk, int C,
                                                       const float* __restrict__ gamma,
                                                       const float* __restrict__ beta,
                                                       float* __restrict__ scale,
                                                       float* __restrict__ shift) {
  int c = blockIdx.x;
  float s = 0.f, q = 0.f;
  for (int i = threadIdx.x; i < nblk; i += 256) {
    const float* p = partials + (size_t)i * 2 * C;
    s += p[c];
    q += p[C + c];
  }
  __shared__ float rs[256], rq[256];
  rs[threadIdx.x] = s;
  rq[threadIdx.x] = q;
  __syncthreads();
  for (int st = 128; st > 0; st >>= 1) {
    if (threadIdx.x < st) {
      rs[threadIdx.x] += rs[threadIdx.x + st];
      rq[threadIdx.x] += rq[threadIdx.x + st];
    }
    __syncthreads();
  }
  if (threadIdx.x == 0) {
    const float N = 128.0f * 4097.0f;
    float mean = rs[0] / N;
    float var = rq[0] / N - mean * mean;
    float sc = gamma[c] * rsqrtf(var + 1e-5f);
    scale[c] = sc;
    shift[c] = beta[c] - mean * sc;
  }
}

// ---------------- conv2: counted-vmcnt pipeline (T3+T4+T5), HW fp8 cvt ----------
__global__ __launch_bounds__(256, 2) void conv2_kernel(const uint8_t* __restrict__ y1,
                                                       const uint8_t* __restrict__ wp,
                                                       const float* __restrict__ s1,
                                                       const float* __restrict__ t1,
                                                       uint8_t* __restrict__ y2,
                                                       float* __restrict__ partials) {
  __shared__ uint4 xs4[2112];  // 132 rows x 256B bf16, XOR-swizzled
  __shared__ uint4 wb4[1536];  // 3 x 8KB weight ring
  uint8_t* xsb = (uint8_t*)xs4;
  uint8_t* wbuf = (uint8_t*)wb4;
  const int tid = threadIdx.x;
  const int b = blockIdx.z;
  const int h2 = blockIdx.y;
  const int l0 = blockIdx.x * 128;
  const uint8_t* wph = wp + (size_t)h2 * 8192;
  // issue W chunks 0,1 async
  GLOAD_LDS(wph + tid * 16, wbuf + tid * 16);
  GLOAD_LDS(wph + 4096 + tid * 16, wbuf + 4096 + tid * 16);
  GLOAD_LDS(wph + 16384 + tid * 16, wbuf + 8192 + tid * 16);
  GLOAD_LDS(wph + 16384 + 4096 + tid * 16, wbuf + 8192 + 4096 + tid * 16);
  // reg-stage X (fp8 -> BN+ReLU -> bf16 via HW cvt)
  {
    const int c0s = (tid & 15) * 8;
    float scv[8], shv[8];
    *(float4*)scv = *(const float4*)(s1 + c0s);
    *(float4*)(scv + 4) = *(const float4*)(s1 + c0s + 4);
    *(float4*)shv = *(const float4*)(t1 + c0s);
    *(float4*)(shv + 4) = *(const float4*)(t1 + c0s + 4);
    const uint8_t* xrow = y1 + ((size_t)b * LROWS + (ROW0 + l0 - 2)) * 128;
    uint2 raw[9];
#pragma unroll
    for (int it = 0; it < 9; ++it) {
      int u = tid + it * 256;
      if (u < 2112) raw[it] = *(const uint2*)(xrow + (size_t)(u >> 4) * 128 + (u & 15) * 8);
    }
#pragma unroll
    for (int it = 0; it < 9; ++it) {
      int u = tid + it * 256;
      if (u < 2112) {
        int row = u >> 4, g8 = u & 15;
        bool valid = (unsigned)(l0 - 2 + row) < (unsigned)NVALID;
        uint4 p = stage8c(raw[it], scv, shv, valid);
        *(uint4*)(xsb + row * 256 + ((g8 * 16) ^ ((row & 7) << 4))) = p;
      }
    }
  }
  __syncthreads();
  const int lane = tid & 63, wid = tid >> 6;
  const int wr = wid >> 1, wcc = wid & 1;
  const int lrow = lane & 15, lk = lane >> 4;
  const int r0 = wr * 64, c0 = wcc * 64;
  f32x4 acc[4][4] = {};
#pragma unroll
  for (int s = 0; s < 20; ++s) {
    if (s < 18) {  // depth-2 prefetch into ring slot (s+2)%3
      const uint8_t* src = wph + (size_t)(s + 2) * 16384;
      uint8_t* dst = wbuf + ((s + 2) % 3) * 8192;
      GLOAD_LDS(src + tid * 16, dst + tid * 16);
      GLOAD_LDS(src + 4096 + tid * 16, dst + 4096 + tid * 16);
    }
    const int t = s >> 2, kk = s & 3;
    bf16x8 a[4], bb[4];
#pragma unroll
    for (int fr = 0; fr < 4; ++fr) {
      int row = r0 + fr * 16 + lrow + t;
      a[fr] = *(const bf16x8*)(xsb + row * 256 + ((kk * 64 + lk * 16) ^ ((row & 7) << 4)));
    }
    const uint8_t* wc = wbuf + (s % 3) * 8192 + (wcc * 4) * 1024 + (size_t)lane * 16;
#pragma unroll
    for (int fc = 0; fc < 4; ++fc) bb[fc] = *(const bf16x8*)(wc + fc * 1024);
    __builtin_amdgcn_s_setprio(1);
#pragma unroll
    for (int fr = 0; fr < 4; ++fr)
#pragma unroll
      for (int fc = 0; fc < 4; ++fc)
        acc[fr][fc] = __builtin_amdgcn_mfma_f32_16x16x32_bf16(a[fr], bb[fc], acc[fr][fc], 0, 0, 0);
    __builtin_amdgcn_s_setprio(0);
    if (s < 18) {
      asm volatile("s_waitcnt vmcnt(2)" ::: "memory");
    } else {
      asm volatile("s_waitcnt vmcnt(0)" ::: "memory");
    }
    __builtin_amdgcn_s_barrier();
  }
  // epilogue: fp8 (HW pk-encode) into dead X LDS + stats (sred reuses W ring)
  float* sred = (float*)wb4;  // [4][128]
  float ps[4] = {0.f, 0.f, 0.f, 0.f}, pq[4] = {0.f, 0.f, 0.f, 0.f};
#pragma unroll
  for (int fr = 0; fr < 4; ++fr)
#pragma unroll
    for (int fc = 0; fc < 4; ++fc) {
      int col = c0 + fc * 16 + lrow;
      int rbase = r0 + fr * 16 + lk * 4;
#pragma unroll
      for (int rg = 0; rg < 4; rg += 2) {
        float v0 = acc[fr][fc][rg], v1 = acc[fr][fc][rg + 1];
        unsigned pk = __builtin_amdgcn_cvt_pk_fp8_f32(v0, v1, 0, false);
        xsb[(rbase + rg) * 128 + col] = (uint8_t)pk;
        xsb[(rbase + rg + 1) * 128 + col] = (uint8_t)(pk >> 8);
        if (l0 + rbase + rg < NVALID) {
          ps[fc] += v0;
          pq[fc] += v0 * v0;
        }
        if (l0 + rbase + rg + 1 < NVALID) {
          ps[fc] += v1;
          pq[fc] += v1 * v1;
        }
      }
    }
#pragma unroll
  for (int fc = 0; fc < 4; ++fc) {
    float s = ps[fc], q = pq[fc];
    s += __shfl_xor(s, 16); s += __shfl_xor(s, 32);
    q += __shfl_xor(q, 16); q += __shfl_xor(q, 32);
    if (lk == 0) {
      int col = c0 + fc * 16 + lrow;
      sred[(wr * 2 + 0) * 128 + col] = s;
      sred[(wr * 2 + 1) * 128 + col] = q;
    }
  }
  __syncthreads();
  {
    uint8_t* yb = y2 + ((size_t)b * LROWS + (ROW0 + l0)) * 256 + h2 * 128;
    int row = tid >> 1, q = tid & 1;
    const uint8_t* src = xsb + row * 128 + q * 64;
    uint8_t* dst = yb + (size_t)row * 256 + q * 64;
    uint4 v0 = *(const uint4*)(src);
    uint4 v1 = *(const uint4*)(src + 16);
    uint4 v2 = *(const uint4*)(src + 32);
    uint4 v3 = *(const uint4*)(src + 48);
    *(uint4*)(dst) = v0;
    *(uint4*)(dst + 16) = v1;
    *(uint4*)(dst + 32) = v2;
    *(uint4*)(dst + 48) = v3;
  }
  if (tid < 128) {
    float* pb = partials + ((size_t)b * 33 + blockIdx.x) * 512;
    pb[h2 * 128 + tid] = sred[0 * 128 + tid] + sred[2 * 128 + tid];
    pb[256 + h2 * 128 + tid] = sred[1 * 128 + tid] + sred[3 * 128 + tid];
  }
}

// ---------------- conv3: counted-vmcnt pipeline, 2 channel-halves, HW cvt -------
__global__ __launch_bounds__(256, 2) void conv3_kernel(const uint8_t* __restrict__ y2,
                                                       const uint8_t* __restrict__ wp,
                                                       const float* __restrict__ s2,
                                                       const float* __restrict__ t2,
                                                       uint8_t* __restrict__ y3,
                                                       float* __restrict__ partials) {
  __shared__ uint4 xs4[2080];  // 130 rows x 256B (one 128-ch half), swizzled
  __shared__ uint4 wb4[1536];  // 3 x 8KB ring
  uint8_t* xsb = (uint8_t*)xs4;
  uint8_t* wbuf = (uint8_t*)wb4;
  const int tid = threadIdx.x;
  const int b = blockIdx.z;
  const int l0 = blockIdx.x * 128;
  const uint8_t* xrowbase = y2 + ((size_t)b * LROWS + (ROW0 + l0 - 1)) * 256;
  const int c0s = (tid & 15) * 8;
#define W3BASE(n) ((size_t)((((n) % 12) >> 2) * 8 + ((n) / 12) * 4 + ((n) & 3)) * 8192)
  GLOAD_LDS(wp + W3BASE(0) + tid * 16, wbuf + tid * 16);
  GLOAD_LDS(wp + W3BASE(0) + 4096 + tid * 16, wbuf + 4096 + tid * 16);
  GLOAD_LDS(wp + W3BASE(1) + tid * 16, wbuf + 8192 + tid * 16);
  GLOAD_LDS(wp + W3BASE(1) + 4096 + tid * 16, wbuf + 8192 + 4096 + tid * 16);
  // stage X half-0
  {
    float scv[8], shv[8];
    *(float4*)scv = *(const float4*)(s2 + c0s);
    *(float4*)(scv + 4) = *(const float4*)(s2 + c0s + 4);
    *(float4*)shv = *(const float4*)(t2 + c0s);
    *(float4*)(shv + 4) = *(const float4*)(t2 + c0s + 4);
    uint2 raw[9];
#pragma unroll
    for (int it = 0; it < 9; ++it) {
      int u = tid + it * 256;
      if (u < 2080) raw[it] = *(const uint2*)(xrowbase + (size_t)(u >> 4) * 256 + (u & 15) * 8);
    }
#pragma unroll
    for (int it = 0; it < 9; ++it) {
      int u = tid + it * 256;
      if (u < 2080) {
        int row = u >> 4, g8 = u & 15;
        bool valid = (unsigned)(l0 - 1 + row) < (unsigned)NVALID;
        uint4 p = stage8c(raw[it], scv, shv, valid);
        *(uint4*)(xsb + row * 256 + ((g8 * 16) ^ ((row & 7) << 4))) = p;
      }
    }
  }
  __syncthreads();
  const int lane = tid & 63, wid = tid >> 6;
  const int wr = wid >> 1, wcc = wid & 1;
  const int lrow = lane & 15, lk = lane >> 4;
  const int r0 = wr * 64, c0 = wcc * 64;
  f32x4 acc[4][4] = {};
#define C3STEP(S)                                                                       \
  {                                                                                     \
    if ((S) < 22) {                                                                     \
      const uint8_t* src = wp + W3BASE((S) + 2);                                        \
      uint8_t* dst = wbuf + (((S) + 2) % 3) * 8192;                                     \
      GLOAD_LDS(src + tid * 16, dst + tid * 16);                                        \
      GLOAD_LDS(src + 4096 + tid * 16, dst + 4096 + tid * 16);                          \
    }                                                                                   \
    const int t_ = ((S) % 12) >> 2, kq_ = (S) & 3;                                      \
    bf16x8 a[4], bb[4];                                                                 \
    _Pragma("unroll") for (int fr = 0; fr < 4; ++fr) {                                  \
      int row = r0 + fr * 16 + lrow + t_;                                               \
      a[fr] = *(const bf16x8*)(xsb + row * 256 +                                        \
                               ((kq_ * 64 + lk * 16) ^ ((row & 7) << 4)));              \
    }                                                                                   \
    const uint8_t* wc = wbuf + ((S) % 3) * 8192 + (wcc * 4) * 1024 + (size_t)lane * 16; \
    _Pragma("unroll") for (int fc = 0; fc < 4; ++fc) bb[fc] = *(const bf16x8*)(wc + fc * 1024); \
    __builtin_amdgcn_s_setprio(1);                                                      \
    _Pragma("unroll") for (int fr = 0; fr < 4; ++fr)                                    \
        _Pragma("unroll") for (int fc = 0; fc < 4; ++fc)                                \
            acc[fr][fc] =                                                               \
                __builtin_amdgcn_mfma_f32_16x16x32_bf16(a[fr], bb[fc], acc[fr][fc], 0, 0, 0); \
    __builtin_amdgcn_s_setprio(0);                                                      \
    if ((S) < 22) {                                                                     \
      asm volatile("s_waitcnt vmcnt(2)" ::: "memory");                                  \
    } else {                                                                            \
      asm volatile("s_waitcnt vmcnt(0)" ::: "memory");                                  \
    }                                                                                   \
    __builtin_amdgcn_s_barrier();                                                       \
  }
#pragma unroll
  for (int s = 0; s < 12; ++s) C3STEP(s);
  // restage X with half-1 channels
  {
    float scv[8], shv[8];
    *(float4*)scv = *(const float4*)(s2 + 128 + c0s);
    *(float4*)(scv + 4) = *(const float4*)(s2 + 128 + c0s + 4);
    *(float4*)shv = *(const float4*)(t2 + 128 + c0s);
    *(float4*)(shv + 4) = *(const float4*)(t2 + 128 + c0s + 4);
    uint2 raw[9];
#pragma unroll
    for (int it = 0; it < 9; ++it) {
      int u = tid + it * 256;
      if (u < 2080)
        raw[it] = *(const uint2*)(xrowbase + (size_t)(u >> 4) * 256 + 128 + (u & 15) * 8);
    }
#pragma unroll
    for (int it = 0; it < 9; ++it) {
      int u = tid + it * 256;
      if (u < 2080) {
        int row = u >> 4, g8 = u & 15;
        bool valid = (unsigned)(l0 - 1 + row) < (unsigned)NVALID;
        uint4 p = stage8c(raw[it], scv, shv, valid);
        *(uint4*)(xsb + row * 256 + ((g8 * 16) ^ ((row & 7) << 4))) = p;
      }
    }
  }
  __syncthreads();
#pragma unroll
  for (int s = 12; s < 24; ++s) C3STEP(s);
  // epilogue
  float* sred = (float*)wb4;  // [4][128]
  float ps[4] = {0.f, 0.f, 0.f, 0.f}, pq[4] = {0.f, 0.f, 0.f, 0.f};
#pragma unroll
  for (int fr = 0; fr < 4; ++fr)
#pragma unroll
    for (int fc = 0; fc < 4; ++fc) {
      int col = c0 + fc * 16 + lrow;
      int rbase = r0 + fr * 16 + lk * 4;
#pragma unroll
      for (int rg = 0; rg < 4; rg += 2) {
        float v0 = acc[fr][fc][rg], v1 = acc[fr][fc][rg + 1];
        unsigned pk = __builtin_amdgcn_cvt_pk_fp8_f32(v0, v1, 0, false);
        xsb[(rbase + rg) * 128 + col] = (uint8_t)pk;
        xsb[(rbase + rg + 1) * 128 + col] = (uint8_t)(pk >> 8);
        if (l0 + rbase + rg < NVALID) {
          ps[fc] += v0;
          pq[fc] += v0 * v0;
        }
        if (l0 + rbase + rg + 1 < NVALID) {
          ps[fc] += v1;
          pq[fc] += v1 * v1;
        }
      }
    }
#pragma unroll
  for (int fc = 0; fc < 4; ++fc) {
    float s = ps[fc], q = pq[fc];
    s += __shfl_xor(s, 16); s += __shfl_xor(s, 32);
    q += __shfl_xor(q, 16); q += __shfl_xor(q, 32);
    if (lk == 0) {
      int col = c0 + fc * 16 + lrow;
      sred[(wr * 2 + 0) * 128 + col] = s;
      sred[(wr * 2 + 1) * 128 + col] = q;
    }
  }
  __syncthreads();
  {
    uint8_t* yb = y3 + ((size_t)b * LROWS + (ROW0 + l0)) * 128;
    int row = tid >> 1, q = tid & 1;
    const uint8_t* src = xsb + row * 128 + q * 64;
    uint8_t* dst = yb + (size_t)row * 128 + q * 64;
    uint4 v0 = *(const uint4*)(src);
    uint4 v1 = *(const uint4*)(src + 16);
    uint4 v2 = *(const uint4*)(src + 32);
    uint4 v3 = *(const uint4*)(src + 48);
    *(uint4*)(dst) = v0;
    *(uint4*)(dst + 16) = v1;
    *(uint4*)(dst + 32) = v2;
    *(uint4*)(dst + 48) = v3;
  }
  if (tid < 128) {
    float* pb = partials + ((size_t)b * 33 + blockIdx.x) * 256;
    pb[tid] = sred[0 * 128 + tid] + sred[2 * 128 + tid];
    pb[128 + tid] = sred[1 * 128 + tid] + sred[3 * 128 + tid];
  }
}

// ---------------- feat: BN3+ReLU fused into length-mean partials ----------------
__global__ __launch_bounds__(256) void feat_kernel(const uint8_t* __restrict__ y3,
                                                   const float* __restrict__ s3,
                                                   const float* __restrict__ t3,
                                                   float* __restrict__ fpart) {
  const int b = blockIdx.y, chk = blockIdx.x;
  const int cq = threadIdx.x & 31, lg = threadIdx.x >> 5;
  const uint8_t* base = y3 + ((size_t)b * LROWS + ROW0) * 128;
  float sc[4], sh[4], acc[4] = {0.f, 0.f, 0.f, 0.f};
#pragma unroll
  for (int ci = 0; ci < 4; ++ci) {
    sc[ci] = s3[cq * 4 + ci];
    sh[ci] = t3[cq * 4 + ci];
  }
  int lstart = chk * 513, lend = lstart + 513;
  if (lend > NVALID) lend = NVALID;
  for (int l = lstart + lg; l < lend; l += 8) {
    unsigned u = *(const unsigned*)(base + (size_t)l * 128 + cq * 4);
    f32x2 d0 = __builtin_amdgcn_cvt_pk_f32_fp8(u, false);
    f32x2 d1 = __builtin_amdgcn_cvt_pk_f32_fp8(u, true);
    acc[0] += fmaxf(fmaf(d0.x, sc[0], sh[0]), 0.f);
    acc[1] += fmaxf(fmaf(d0.y, sc[1], sh[1]), 0.f);
    acc[2] += fmaxf(fmaf(d1.x, sc[2], sh[2]), 0.f);
    acc[3] += fmaxf(fmaf(d1.y, sc[3], sh[3]), 0.f);
  }
  __shared__ float red[8][128];
#pragma unroll
  for (int ci = 0; ci < 4; ++ci) red[lg][cq * 4 + ci] = acc[ci];
  __syncthreads();
  if (threadIdx.x < 128) {
    float sum = 0.f;
#pragma unroll
    for (int g = 0; g < 8; ++g) sum += red[g][threadIdx.x];
    fpart[((size_t)chk * 128 + b) * 128 + threadIdx.x] = sum;
  }
}

// ---------------- head: NALU x2 + final linear (fp32) ---------------------------
__global__ __launch_bounds__(128) void head_kernel(const float* __restrict__ fpart,
                                                   const float* __restrict__ W1,
                                                   const float* __restrict__ G1,
                                                   const float* __restrict__ W2,
                                                   const float* __restrict__ G2,
                                                   const float* __restrict__ fw,
                                                   const float* __restrict__ fb,
                                                   float* __restrict__ out) {
  const int b = blockIdx.x, j = threadIdx.x;
  __shared__ float xs[128], lxs[128], h1[128], lh1[128], h2[16];
  float x = 0.f;
#pragma unroll
  for (int chk = 0; chk < 8; ++chk) x += fpart[((size_t)chk * 128 + b) * 128 + j];
  x *= (1.0f / 4097.0f);
  xs[j] = x;
  lxs[j] = logf(fabsf(x) + 1e-10f);
  __syncthreads();
  float a = 0.f, me = 0.f, ga = 0.f;
  for (int i = 0; i < 128; ++i) {
    float w = W1[j * 128 + i];
    a += xs[i] * w;
    me += lxs[i] * w;
    ga += xs[i] * G1[j * 128 + i];
  }
  float g = 1.0f / (1.0f + expf(-ga));
  float h = g * a + (1.0f - g) * expf(me);
  h1[j] = h;
  lh1[j] = logf(fabsf(h) + 1e-10f);
  __syncthreads();
  if (j < 16) {
    float a2 = 0.f, m2 = 0.f, g2 = 0.f;
    for (int i = 0; i < 128; ++i) {
      float w = W2[j * 128 + i];
      a2 += h1[i] * w;
      m2 += lh1[i] * w;
      g2 += h1[i] * G2[j * 128 + i];
    }
    float gg = 1.0f / (1.0f + expf(-g2));
    h2[j] = gg * a2 + (1.0f - gg) * expf(m2);
  }
  __syncthreads();
  if (j == 0) {
    float o = fb[0];
#pragma unroll
    for (int i = 0; i < 16; ++i) o += h2[i] * fw[i];
    out[b] = o;
  }
}

// ---------------- launch --------------------------------------------------------
extern "C" void kernel_launch(void* const* d_in, const int* in_sizes, int n_in,
                              void* d_out, int out_size, void* d_ws, size_t ws_size,
                              hipStream_t stream) {
  (void)in_sizes; (void)n_in; (void)out_size; (void)ws_size;
  const float* inp = (const float*)d_in[0];
  const float* w1  = (const float*)d_in[1];
  const float* g1  = (const float*)d_in[3];
  const float* b1  = (const float*)d_in[4];
  const float* w2  = (const float*)d_in[5];
  const float* g2  = (const float*)d_in[7];
  const float* b2  = (const float*)d_in[8];
  const float* w3  = (const float*)d_in[9];
  const float* g3  = (const float*)d_in[11];
  const float* b3  = (const float*)d_in[12];
  const float* wh1 = (const float*)d_in[13];
  const float* mh1 = (const float*)d_in[14];
  const float* G1  = (const float*)d_in[15];
  const float* wh2 = (const float*)d_in[16];
  const float* mh2 = (const float*)d_in[17];
  const float* G2  = (const float*)d_in[18];
  const float* fw  = (const float*)d_in[19];
  const float* fb  = (const float*)d_in[20];
  float* out = (float*)d_out;

  uint8_t* ws = (uint8_t*)d_ws;
  size_t off = 0;
  auto alloc = [&](size_t n) {
    uint8_t* p = ws + off;
    off += (n + 255) & ~(size_t)255;
    return p;
  };
  uint8_t* y1  = alloc((size_t)128 * LROWS * 128);   // fp8; later aliased as y3
  uint8_t* y2  = alloc((size_t)128 * LROWS * 256);   // fp8
  uint8_t* w2p = alloc((size_t)320 * 1024);
  uint8_t* w3p = alloc((size_t)192 * 1024);
  float* part1 = (float*)alloc((size_t)2176 * 256 * 4);
  float* part2 = (float*)alloc((size_t)4224 * 512 * 4);
  float* part3 = (float*)alloc((size_t)4224 * 256 * 4);
  float* s1 = (float*)alloc(128 * 4); float* t1 = (float*)alloc(128 * 4);
  float* s2 = (float*)alloc(256 * 4); float* t2 = (float*)alloc(256 * 4);
  float* s3 = (float*)alloc(128 * 4); float* t3 = (float*)alloc(128 * 4);
  float* fpart = (float*)alloc((size_t)8 * 128 * 128 * 4);
  float* W1n = (float*)alloc(128 * 128 * 4);
  float* W2n = (float*)alloc(16 * 128 * 4);
  uint8_t* y3 = y1;  // alias: y1 dead once conv2 done

  prepack_w2_kernel<<<640, 256, 0, stream>>>(w2, w2p);
  prepack_w3_kernel<<<384, 256, 0, stream>>>(w3, w3p);
  prep_nalu_kernel<<<72, 256, 0, stream>>>(wh1, mh1, wh2, mh2, W1n, W2n);

  conv1_kernel<<<dim3(17, 128), 256, 0, stream>>>(inp, w1, y1, part1);
  finalize_kernel<<<128, 256, 0, stream>>>(part1, 2176, 128, g1, b1, s1, t1);

  conv2_kernel<<<dim3(33, 2, 128), 256, 0, stream>>>(y1, w2p, s1, t1, y2, part2);
  finalize_kernel<<<256, 256, 0, stream>>>(part2, 4224, 256, g2, b2, s2, t2);

  conv3_kernel<<<dim3(33, 1, 128), 256, 0, stream>>>(y2, w3p, s2, t2, y3, part3);
  finalize_kernel<<<128, 256, 0, stream>>>(part3, 4224, 128, g3, b3, s3, t3);

  feat_kernel<<<dim3(8, 128), 256, 0, stream>>>(y3, s3, t3, fpart);
  head_kernel<<<128, 128, 0, stream>>>(fpart, W1n, G1, W2n, G2, fw, fb, out);
}

// Round 10
// 525.861 us; speedup vs baseline: 3.1405x; 1.0319x over previous
//
#include <hip/hip_runtime.h>
#include <stdint.h>

#define LROWS 4240
#define ROW0 8
#define NVALID 4097

typedef float f32x4 __attribute__((ext_vector_type(4)));
typedef float f32x2 __attribute__((ext_vector_type(2)));
typedef short bf16x8 __attribute__((ext_vector_type(8)));

#define GLOAD_LDS(gaddr, laddr)                                                            \
  __builtin_amdgcn_global_load_lds((const __attribute__((address_space(1))) void*)(gaddr), \
                                   (__attribute__((address_space(3))) void*)(laddr), 16, 0, 0)

__device__ __forceinline__ unsigned short f2bf(float f) {
  unsigned u = __float_as_uint(f);
  u += 0x7fffu + ((u >> 16) & 1u);
  return (unsigned short)(u >> 16);
}

// decode 8 fp8 (uint2) + BN + ReLU -> 8 bf16 packed in uint4, via HW converters
__device__ __forceinline__ uint4 stage8c(uint2 raw, const float* __restrict__ sc8,
                                         const float* __restrict__ sh8, bool valid) {
  f32x2 d[4];
  d[0] = __builtin_amdgcn_cvt_pk_f32_fp8(raw.x, false);
  d[1] = __builtin_amdgcn_cvt_pk_f32_fp8(raw.x, true);
  d[2] = __builtin_amdgcn_cvt_pk_f32_fp8(raw.y, false);
  d[3] = __builtin_amdgcn_cvt_pk_f32_fp8(raw.y, true);
  uint4 outv;
  unsigned* o = (unsigned*)&outv;
#pragma unroll
  for (int p = 0; p < 4; ++p) {
    float lo = valid ? fmaxf(fmaf(d[p].x, sc8[2 * p], sh8[2 * p]), 0.f) : 0.f;
    float hi = valid ? fmaxf(fmaf(d[p].y, sc8[2 * p + 1], sh8[2 * p + 1]), 0.f) : 0.f;
    unsigned r;
    asm("v_cvt_pk_bf16_f32 %0, %1, %2" : "=v"(r) : "v"(lo), "v"(hi));
    o[p] = r;
  }
  return outv;
}

// ---------------- weight prepack: per-(K-step, colgroup) 1KB fragment blobs ----
__global__ void prepack_w2_kernel(const float* __restrict__ w2, uint8_t* __restrict__ wp) {
  int i = blockIdx.x * 256 + threadIdx.x;
  if (i >= 163840) return;
  int t = i % 5, oc = i / 5;
  int cin = oc & 127, o = oc >> 7;
  int step = t * 4 + (cin >> 5);
  int og = o >> 4;
  int lane = ((cin >> 3) & 3) * 16 + (o & 15);
  int j = cin & 7;
  *(unsigned short*)(wp + ((size_t)(step * 16 + og) << 10) + lane * 16 + j * 2) = f2bf(w2[i]);
}
__global__ void prepack_w3_kernel(const float* __restrict__ w3, uint8_t* __restrict__ wp) {
  int i = blockIdx.x * 256 + threadIdx.x;
  if (i >= 98304) return;
  int t = i % 3, oc = i / 3;
  int cin = oc & 255, o = oc >> 8;
  int step = t * 8 + (cin >> 5);
  int og = o >> 4;
  int lane = ((cin >> 3) & 3) * 16 + (o & 15);
  int j = cin & 7;
  *(unsigned short*)(wp + ((size_t)(step * 8 + og) << 10) + lane * 16 + j * 2) = f2bf(w3[i]);
}

__global__ void prep_nalu_kernel(const float* __restrict__ wh1, const float* __restrict__ mh1,
                                 const float* __restrict__ wh2, const float* __restrict__ mh2,
                                 float* __restrict__ W1, float* __restrict__ W2) {
  int i = blockIdx.x * 256 + threadIdx.x;
  if (i < 16384) {
    W1[i] = tanhf(wh1[i]) * (1.0f / (1.0f + expf(-mh1[i])));
  } else if (i < 18432) {
    int k = i - 16384;
    W2[k] = tanhf(wh2[k]) * (1.0f / (1.0f + expf(-mh2[k])));
  }
}

// ---------------- conv1: C_in=1, k=8 fp32 vector -> y1 fp8 + stats --------------
__global__ __launch_bounds__(256) void conv1_kernel(const float* __restrict__ inp,
                                                    const float* __restrict__ w1,
                                                    uint8_t* __restrict__ y1,
                                                    float* __restrict__ partials) {
  __shared__ float xsh[272];
  __shared__ float reds[2][8][128];
  const int tid = threadIdx.x;
  const int b = blockIdx.y;
  const int l0 = blockIdx.x * 256;
  const float* xb = inp + (size_t)b * 4096;
  for (int j = tid; j < 263; j += 256) {
    int li = l0 - 4 + j;
    xsh[j] = ((unsigned)li < 4096u) ? xb[li] : 0.f;
  }
  __syncthreads();
  const int cg = tid & 31, lsub = tid >> 5;
  float w[4][8];
#pragma unroll
  for (int ci = 0; ci < 4; ++ci)
#pragma unroll
    for (int t = 0; t < 8; ++t) w[ci][t] = w1[(cg * 4 + ci) * 8 + t];
  float s[4] = {0.f, 0.f, 0.f, 0.f}, q[4] = {0.f, 0.f, 0.f, 0.f};
  uint8_t* yb = y1 + ((size_t)b * LROWS + (ROW0 + l0)) * 128;
  for (int li = lsub; li < 256; li += 8) {
    if (l0 + li >= NVALID) break;
    float av[4];
#pragma unroll
    for (int ci = 0; ci < 4; ++ci) {
      float a = 0.f;
#pragma unroll
      for (int t = 0; t < 8; ++t) a += xsh[li + t] * w[ci][t];
      s[ci] += a;
      q[ci] += a * a;
      av[ci] = a;
    }
    unsigned pk = __builtin_amdgcn_cvt_pk_fp8_f32(av[0], av[1], 0, false);
    pk = __builtin_amdgcn_cvt_pk_fp8_f32(av[2], av[3], pk, true);
    *(unsigned*)(yb + (size_t)li * 128 + cg * 4) = pk;
  }
#pragma unroll
  for (int ci = 0; ci < 4; ++ci) {
    reds[0][lsub][cg * 4 + ci] = s[ci];
    reds[1][lsub][cg * 4 + ci] = q[ci];
  }
  __syncthreads();
  if (tid < 128) {
    float ss = 0.f, qq = 0.f;
#pragma unroll
    for (int g = 0; g < 8; ++g) {
      ss += reds[0][g][tid];
      qq += reds[1][g][tid];
    }
    float* pb = partials + ((size_t)b * 17 + blockIdx.x) * 256;
    pb[tid] = ss;
    pb[128 + tid] = qq;
  }
}

// ---------------- BN finalize ---------------------------------------------------
__global__ __launch_bounds__(256) void finalize_kernel(const float* __restrict__ partials,
                                                       int nblk, int C,
                                                       const float* __restrict__ gamma,
                                                       const float* __restrict__ beta,
                                                       float* __restrict__ scale,
                                                       float* __restrict__ shift) {
  int c = blockIdx.x;
  float s = 0.f, q = 0.f;
  for (int i = threadIdx.x; i < nblk; i += 256) {
    const float* p = partials + (size_t)i * 2 * C;
    s += p[c];
    q += p[C + c];
  }
  __shared__ float rs[256], rq[256];
  rs[threadIdx.x] = s;
  rq[threadIdx.x] = q;
  __syncthreads();
  for (int st = 128; st > 0; st >>= 1) {
    if (threadIdx.x < st) {
      rs[threadIdx.x] += rs[threadIdx.x + st];
      rq[threadIdx.x] += rq[threadIdx.x + st];
    }
    __syncthreads();
  }
  if (threadIdx.x == 0) {
    const float N = 128.0f * 4097.0f;
    float mean = rs[0] / N;
    float var = rq[0] / N - mean * mean;
    float sc = gamma[c] * rsqrtf(var + 1e-5f);
    scale[c] = sc;
    shift[c] = beta[c] - mean * sc;
  }
}

// ---------------- conv2: counted-vmcnt pipeline, 96-row tile, 3 blocks/CU -------
// 256 thr, 4 waves (2x2), wave 48x64; tile 96 rows x 128 cout (h2 = cout half).
__global__ __launch_bounds__(256, 3) void conv2_kernel(const uint8_t* __restrict__ y1,
                                                       const uint8_t* __restrict__ wp,
                                                       const float* __restrict__ s1,
                                                       const float* __restrict__ t1,
                                                       uint8_t* __restrict__ y2,
                                                       float* __restrict__ partials) {
  __shared__ uint4 xs4[1600];  // 100 rows x 256B bf16, XOR-swizzled (25600 B)
  __shared__ uint4 wb4[1536];  // 3 x 8KB weight ring
  uint8_t* xsb = (uint8_t*)xs4;
  uint8_t* wbuf = (uint8_t*)wb4;
  const int tid = threadIdx.x;
  const int b = blockIdx.z;
  const int h2 = blockIdx.y;
  const int l0 = blockIdx.x * 96;
  const uint8_t* wph = wp + (size_t)h2 * 8192;
  // issue W chunks 0,1 async
  GLOAD_LDS(wph + tid * 16, wbuf + tid * 16);
  GLOAD_LDS(wph + 4096 + tid * 16, wbuf + 4096 + tid * 16);
  GLOAD_LDS(wph + 16384 + tid * 16, wbuf + 8192 + tid * 16);
  GLOAD_LDS(wph + 16384 + 4096 + tid * 16, wbuf + 8192 + 4096 + tid * 16);
  // reg-stage X (fp8 -> BN+ReLU -> bf16 via HW cvt)
  {
    const int c0s = (tid & 15) * 8;
    float scv[8], shv[8];
    *(float4*)scv = *(const float4*)(s1 + c0s);
    *(float4*)(scv + 4) = *(const float4*)(s1 + c0s + 4);
    *(float4*)shv = *(const float4*)(t1 + c0s);
    *(float4*)(shv + 4) = *(const float4*)(t1 + c0s + 4);
    const uint8_t* xrow = y1 + ((size_t)b * LROWS + (ROW0 + l0 - 2)) * 128;
    uint2 raw[7];
#pragma unroll
    for (int it = 0; it < 7; ++it) {
      int u = tid + it * 256;
      if (u < 1600) raw[it] = *(const uint2*)(xrow + (size_t)(u >> 4) * 128 + (u & 15) * 8);
    }
#pragma unroll
    for (int it = 0; it < 7; ++it) {
      int u = tid + it * 256;
      if (u < 1600) {
        int row = u >> 4, g8 = u & 15;
        bool valid = (unsigned)(l0 - 2 + row) < (unsigned)NVALID;
        uint4 p = stage8c(raw[it], scv, shv, valid);
        *(uint4*)(xsb + row * 256 + ((g8 * 16) ^ ((row & 7) << 4))) = p;
      }
    }
  }
  __syncthreads();
  const int lane = tid & 63, wid = tid >> 6;
  const int wr = wid >> 1, wcc = wid & 1;
  const int lrow = lane & 15, lk = lane >> 4;
  const int r0 = wr * 48, c0 = wcc * 64;
  f32x4 acc[3][4] = {};
#pragma unroll
  for (int s = 0; s < 20; ++s) {
    if (s < 18) {  // depth-2 prefetch into ring slot (s+2)%3
      const uint8_t* src = wph + (size_t)(s + 2) * 16384;
      uint8_t* dst = wbuf + ((s + 2) % 3) * 8192;
      GLOAD_LDS(src + tid * 16, dst + tid * 16);
      GLOAD_LDS(src + 4096 + tid * 16, dst + 4096 + tid * 16);
    }
    const int t = s >> 2, kk = s & 3;
    bf16x8 a[3], bb[4];
#pragma unroll
    for (int fr = 0; fr < 3; ++fr) {
      int row = r0 + fr * 16 + lrow + t;
      a[fr] = *(const bf16x8*)(xsb + row * 256 + ((kk * 64 + lk * 16) ^ ((row & 7) << 4)));
    }
    const uint8_t* wc = wbuf + (s % 3) * 8192 + (wcc * 4) * 1024 + (size_t)lane * 16;
#pragma unroll
    for (int fc = 0; fc < 4; ++fc) bb[fc] = *(const bf16x8*)(wc + fc * 1024);
    __builtin_amdgcn_s_setprio(1);
#pragma unroll
    for (int fr = 0; fr < 3; ++fr)
#pragma unroll
      for (int fc = 0; fc < 4; ++fc)
        acc[fr][fc] = __builtin_amdgcn_mfma_f32_16x16x32_bf16(a[fr], bb[fc], acc[fr][fc], 0, 0, 0);
    __builtin_amdgcn_s_setprio(0);
    if (s < 18) {
      asm volatile("s_waitcnt vmcnt(2)" ::: "memory");
    } else {
      asm volatile("s_waitcnt vmcnt(0)" ::: "memory");
    }
    __builtin_amdgcn_s_barrier();
  }
  // epilogue: fp8 (HW pk-encode) into dead X LDS + stats (sred reuses W ring)
  float* sred = (float*)wb4;  // [4][128]
  float ps[4] = {0.f, 0.f, 0.f, 0.f}, pq[4] = {0.f, 0.f, 0.f, 0.f};
#pragma unroll
  for (int fr = 0; fr < 3; ++fr)
#pragma unroll
    for (int fc = 0; fc < 4; ++fc) {
      int col = c0 + fc * 16 + lrow;
      int rbase = r0 + fr * 16 + lk * 4;
#pragma unroll
      for (int rg = 0; rg < 4; rg += 2) {
        float v0 = acc[fr][fc][rg], v1 = acc[fr][fc][rg + 1];
        unsigned pk = __builtin_amdgcn_cvt_pk_fp8_f32(v0, v1, 0, false);
        xsb[(rbase + rg) * 128 + col] = (uint8_t)pk;
        xsb[(rbase + rg + 1) * 128 + col] = (uint8_t)(pk >> 8);
        if (l0 + rbase + rg < NVALID) {
          ps[fc] += v0;
          pq[fc] += v0 * v0;
        }
        if (l0 + rbase + rg + 1 < NVALID) {
          ps[fc] += v1;
          pq[fc] += v1 * v1;
        }
      }
    }
#pragma unroll
  for (int fc = 0; fc < 4; ++fc) {
    float s = ps[fc], q = pq[fc];
    s += __shfl_xor(s, 16); s += __shfl_xor(s, 32);
    q += __shfl_xor(q, 16); q += __shfl_xor(q, 32);
    if (lk == 0) {
      int col = c0 + fc * 16 + lrow;
      sred[(wr * 2 + 0) * 128 + col] = s;
      sred[(wr * 2 + 1) * 128 + col] = q;
    }
  }
  __syncthreads();
  if (tid < 192) {
    uint8_t* yb = y2 + ((size_t)b * LROWS + (ROW0 + l0)) * 256 + h2 * 128;
    int row = tid >> 1, q = tid & 1;
    const uint8_t* src = xsb + row * 128 + q * 64;
    uint8_t* dst = yb + (size_t)row * 256 + q * 64;
    uint4 v0 = *(const uint4*)(src);
    uint4 v1 = *(const uint4*)(src + 16);
    uint4 v2 = *(const uint4*)(src + 32);
    uint4 v3 = *(const uint4*)(src + 48);
    *(uint4*)(dst) = v0;
    *(uint4*)(dst + 16) = v1;
    *(uint4*)(dst + 32) = v2;
    *(uint4*)(dst + 48) = v3;
  }
  if (tid < 128) {
    float* pb = partials + ((size_t)b * 43 + blockIdx.x) * 512;
    pb[h2 * 128 + tid] = sred[0 * 128 + tid] + sred[2 * 128 + tid];
    pb[256 + h2 * 128 + tid] = sred[1 * 128 + tid] + sred[3 * 128 + tid];
  }
}

// ---------------- conv3: counted-vmcnt pipeline, 96-row tile, 2 ch-halves -------
__global__ __launch_bounds__(256, 3) void conv3_kernel(const uint8_t* __restrict__ y2,
                                                       const uint8_t* __restrict__ wp,
                                                       const float* __restrict__ s2,
                                                       const float* __restrict__ t2,
                                                       uint8_t* __restrict__ y3,
                                                       float* __restrict__ partials) {
  __shared__ uint4 xs4[1568];  // 98 rows x 256B (one 128-ch half), swizzled
  __shared__ uint4 wb4[1536];  // 3 x 8KB ring
  uint8_t* xsb = (uint8_t*)xs4;
  uint8_t* wbuf = (uint8_t*)wb4;
  const int tid = threadIdx.x;
  const int b = blockIdx.z;
  const int l0 = blockIdx.x * 96;
  const uint8_t* xrowbase = y2 + ((size_t)b * LROWS + (ROW0 + l0 - 1)) * 256;
  const int c0s = (tid & 15) * 8;
#define W3BASE(n) ((size_t)((((n) % 12) >> 2) * 8 + ((n) / 12) * 4 + ((n) & 3)) * 8192)
  GLOAD_LDS(wp + W3BASE(0) + tid * 16, wbuf + tid * 16);
  GLOAD_LDS(wp + W3BASE(0) + 4096 + tid * 16, wbuf + 4096 + tid * 16);
  GLOAD_LDS(wp + W3BASE(1) + tid * 16, wbuf + 8192 + tid * 16);
  GLOAD_LDS(wp + W3BASE(1) + 4096 + tid * 16, wbuf + 8192 + 4096 + tid * 16);
  // stage X half-0
  {
    float scv[8], shv[8];
    *(float4*)scv = *(const float4*)(s2 + c0s);
    *(float4*)(scv + 4) = *(const float4*)(s2 + c0s + 4);
    *(float4*)shv = *(const float4*)(t2 + c0s);
    *(float4*)(shv + 4) = *(const float4*)(t2 + c0s + 4);
    uint2 raw[7];
#pragma unroll
    for (int it = 0; it < 7; ++it) {
      int u = tid + it * 256;
      if (u < 1568) raw[it] = *(const uint2*)(xrowbase + (size_t)(u >> 4) * 256 + (u & 15) * 8);
    }
#pragma unroll
    for (int it = 0; it < 7; ++it) {
      int u = tid + it * 256;
      if (u < 1568) {
        int row = u >> 4, g8 = u & 15;
        bool valid = (unsigned)(l0 - 1 + row) < (unsigned)NVALID;
        uint4 p = stage8c(raw[it], scv, shv, valid);
        *(uint4*)(xsb + row * 256 + ((g8 * 16) ^ ((row & 7) << 4))) = p;
      }
    }
  }
  __syncthreads();
  const int lane = tid & 63, wid = tid >> 6;
  const int wr = wid >> 1, wcc = wid & 1;
  const int lrow = lane & 15, lk = lane >> 4;
  const int r0 = wr * 48, c0 = wcc * 64;
  f32x4 acc[3][4] = {};
#define C3STEP(S)                                                                       \
  {                                                                                     \
    if ((S) < 22) {                                                                     \
      const uint8_t* src = wp + W3BASE((S) + 2);                                        \
      uint8_t* dst = wbuf + (((S) + 2) % 3) * 8192;                                     \
      GLOAD_LDS(src + tid * 16, dst + tid * 16);                                        \
      GLOAD_LDS(src + 4096 + tid * 16, dst + 4096 + tid * 16);                          \
    }                                                                                   \
    const int t_ = ((S) % 12) >> 2, kq_ = (S) & 3;                                      \
    bf16x8 a[3], bb[4];                                                                 \
    _Pragma("unroll") for (int fr = 0; fr < 3; ++fr) {                                  \
      int row = r0 + fr * 16 + lrow + t_;                                               \
      a[fr] = *(const bf16x8*)(xsb + row * 256 +                                        \
                               ((kq_ * 64 + lk * 16) ^ ((row & 7) << 4)));              \
    }                                                                                   \
    const uint8_t* wc = wbuf + ((S) % 3) * 8192 + (wcc * 4) * 1024 + (size_t)lane * 16; \
    _Pragma("unroll") for (int fc = 0; fc < 4; ++fc) bb[fc] = *(const bf16x8*)(wc + fc * 1024); \
    __builtin_amdgcn_s_setprio(1);                                                      \
    _Pragma("unroll") for (int fr = 0; fr < 3; ++fr)                                    \
        _Pragma("unroll") for (int fc = 0; fc < 4; ++fc)                                \
            acc[fr][fc] =                                                               \
                __builtin_amdgcn_mfma_f32_16x16x32_bf16(a[fr], bb[fc], acc[fr][fc], 0, 0, 0); \
    __builtin_amdgcn_s_setprio(0);                                                      \
    if ((S) < 22) {                                                                     \
      asm volatile("s_waitcnt vmcnt(2)" ::: "memory");                                  \
    } else {                                                                            \
      asm volatile("s_waitcnt vmcnt(0)" ::: "memory");                                  \
    }                                                                                   \
    __builtin_amdgcn_s_barrier();                                                       \
  }
#pragma unroll
  for (int s = 0; s < 12; ++s) C3STEP(s);
  // restage X with half-1 channels
  {
    float scv[8], shv[8];
    *(float4*)scv = *(const float4*)(s2 + 128 + c0s);
    *(float4*)(scv + 4) = *(const float4*)(s2 + 128 + c0s + 4);
    *(float4*)shv = *(const float4*)(t2 + 128 + c0s);
    *(float4*)(shv + 4) = *(const float4*)(t2 + 128 + c0s + 4);
    uint2 raw[7];
#pragma unroll
    for (int it = 0; it < 7; ++it) {
      int u = tid + it * 256;
      if (u < 1568)
        raw[it] = *(const uint2*)(xrowbase + (size_t)(u >> 4) * 256 + 128 + (u & 15) * 8);
    }
#pragma unroll
    for (int it = 0; it < 7; ++it) {
      int u = tid + it * 256;
      if (u < 1568) {
        int row = u >> 4, g8 = u & 15;
        bool valid = (unsigned)(l0 - 1 + row) < (unsigned)NVALID;
        uint4 p = stage8c(raw[it], scv, shv, valid);
        *(uint4*)(xsb + row * 256 + ((g8 * 16) ^ ((row & 7) << 4))) = p;
      }
    }
  }
  __syncthreads();
#pragma unroll
  for (int s = 12; s < 24; ++s) C3STEP(s);
  // epilogue
  float* sred = (float*)wb4;  // [4][128]
  float ps[4] = {0.f, 0.f, 0.f, 0.f}, pq[4] = {0.f, 0.f, 0.f, 0.f};
#pragma unroll
  for (int fr = 0; fr < 3; ++fr)
#pragma unroll
    for (int fc = 0; fc < 4; ++fc) {
      int col = c0 + fc * 16 + lrow;
      int rbase = r0 + fr * 16 + lk * 4;
#pragma unroll
      for (int rg = 0; rg < 4; rg += 2) {
        float v0 = acc[fr][fc][rg], v1 = acc[fr][fc][rg + 1];
        unsigned pk = __builtin_amdgcn_cvt_pk_fp8_f32(v0, v1, 0, false);
        xsb[(rbase + rg) * 128 + col] = (uint8_t)pk;
        xsb[(rbase + rg + 1) * 128 + col] = (uint8_t)(pk >> 8);
        if (l0 + rbase + rg < NVALID) {
          ps[fc] += v0;
          pq[fc] += v0 * v0;
        }
        if (l0 + rbase + rg + 1 < NVALID) {
          ps[fc] += v1;
          pq[fc] += v1 * v1;
        }
      }
    }
#pragma unroll
  for (int fc = 0; fc < 4; ++fc) {
    float s = ps[fc], q = pq[fc];
    s += __shfl_xor(s, 16); s += __shfl_xor(s, 32);
    q += __shfl_xor(q, 16); q += __shfl_xor(q, 32);
    if (lk == 0) {
      int col = c0 + fc * 16 + lrow;
      sred[(wr * 2 + 0) * 128 + col] = s;
      sred[(wr * 2 + 1) * 128 + col] = q;
    }
  }
  __syncthreads();
  if (tid < 192) {
    uint8_t* yb = y3 + ((size_t)b * LROWS + (ROW0 + l0)) * 128;
    int row = tid >> 1, q = tid & 1;
    const uint8_t* src = xsb + row * 128 + q * 64;
    uint8_t* dst = yb + (size_t)row * 128 + q * 64;
    uint4 v0 = *(const uint4*)(src);
    uint4 v1 = *(const uint4*)(src + 16);
    uint4 v2 = *(const uint4*)(src + 32);
    uint4 v3 = *(const uint4*)(src + 48);
    *(uint4*)(dst) = v0;
    *(uint4*)(dst + 16) = v1;
    *(uint4*)(dst + 32) = v2;
    *(uint4*)(dst + 48) = v3;
  }
  if (tid < 128) {
    float* pb = partials + ((size_t)b * 43 + blockIdx.x) * 256;
    pb[tid] = sred[0 * 128 + tid] + sred[2 * 128 + tid];
    pb[128 + tid] = sred[1 * 128 + tid] + sred[3 * 128 + tid];
  }
}

// ---------------- feat: BN3+ReLU fused into length-mean partials ----------------
__global__ __launch_bounds__(256) void feat_kernel(const uint8_t* __restrict__ y3,
                                                   const float* __restrict__ s3,
                                                   const float* __restrict__ t3,
                                                   float* __restrict__ fpart) {
  const int b = blockIdx.y, chk = blockIdx.x;
  const int cq = threadIdx.x & 31, lg = threadIdx.x >> 5;
  const uint8_t* base = y3 + ((size_t)b * LROWS + ROW0) * 128;
  float sc[4], sh[4], acc[4] = {0.f, 0.f, 0.f, 0.f};
#pragma unroll
  for (int ci = 0; ci < 4; ++ci) {
    sc[ci] = s3[cq * 4 + ci];
    sh[ci] = t3[cq * 4 + ci];
  }
  int lstart = chk * 513, lend = lstart + 513;
  if (lend > NVALID) lend = NVALID;
  for (int l = lstart + lg; l < lend; l += 8) {
    unsigned u = *(const unsigned*)(base + (size_t)l * 128 + cq * 4);
    f32x2 d0 = __builtin_amdgcn_cvt_pk_f32_fp8(u, false);
    f32x2 d1 = __builtin_amdgcn_cvt_pk_f32_fp8(u, true);
    acc[0] += fmaxf(fmaf(d0.x, sc[0], sh[0]), 0.f);
    acc[1] += fmaxf(fmaf(d0.y, sc[1], sh[1]), 0.f);
    acc[2] += fmaxf(fmaf(d1.x, sc[2], sh[2]), 0.f);
    acc[3] += fmaxf(fmaf(d1.y, sc[3], sh[3]), 0.f);
  }
  __shared__ float red[8][128];
#pragma unroll
  for (int ci = 0; ci < 4; ++ci) red[lg][cq * 4 + ci] = acc[ci];
  __syncthreads();
  if (threadIdx.x < 128) {
    float sum = 0.f;
#pragma unroll
    for (int g = 0; g < 8; ++g) sum += red[g][threadIdx.x];
    fpart[((size_t)chk * 128 + b) * 128 + threadIdx.x] = sum;
  }
}

// ---------------- head: NALU x2 + final linear (fp32) ---------------------------
__global__ __launch_bounds__(128) void head_kernel(const float* __restrict__ fpart,
                                                   const float* __restrict__ W1,
                                                   const float* __restrict__ G1,
                                                   const float* __restrict__ W2,
                                                   const float* __restrict__ G2,
                                                   const float* __restrict__ fw,
                                                   const float* __restrict__ fb,
                                                   float* __restrict__ out) {
  const int b = blockIdx.x, j = threadIdx.x;
  __shared__ float xs[128], lxs[128], h1[128], lh1[128], h2[16];
  float x = 0.f;
#pragma unroll
  for (int chk = 0; chk < 8; ++chk) x += fpart[((size_t)chk * 128 + b) * 128 + j];
  x *= (1.0f / 4097.0f);
  xs[j] = x;
  lxs[j] = logf(fabsf(x) + 1e-10f);
  __syncthreads();
  float a = 0.f, me = 0.f, ga = 0.f;
  for (int i = 0; i < 128; ++i) {
    float w = W1[j * 128 + i];
    a += xs[i] * w;
    me += lxs[i] * w;
    ga += xs[i] * G1[j * 128 + i];
  }
  float g = 1.0f / (1.0f + expf(-ga));
  float h = g * a + (1.0f - g) * expf(me);
  h1[j] = h;
  lh1[j] = logf(fabsf(h) + 1e-10f);
  __syncthreads();
  if (j < 16) {
    float a2 = 0.f, m2 = 0.f, g2 = 0.f;
    for (int i = 0; i < 128; ++i) {
      float w = W2[j * 128 + i];
      a2 += h1[i] * w;
      m2 += lh1[i] * w;
      g2 += h1[i] * G2[j * 128 + i];
    }
    float gg = 1.0f / (1.0f + expf(-g2));
    h2[j] = gg * a2 + (1.0f - gg) * expf(m2);
  }
  __syncthreads();
  if (j == 0) {
    float o = fb[0];
#pragma unroll
    for (int i = 0; i < 16; ++i) o += h2[i] * fw[i];
    out[b] = o;
  }
}

// ---------------- launch --------------------------------------------------------
extern "C" void kernel_launch(void* const* d_in, const int* in_sizes, int n_in,
                              void* d_out, int out_size, void* d_ws, size_t ws_size,
                              hipStream_t stream) {
  (void)in_sizes; (void)n_in; (void)out_size; (void)ws_size;
  const float* inp = (const float*)d_in[0];
  const float* w1  = (const float*)d_in[1];
  const float* g1  = (const float*)d_in[3];
  const float* b1  = (const float*)d_in[4];
  const float* w2  = (const float*)d_in[5];
  const float* g2  = (const float*)d_in[7];
  const float* b2  = (const float*)d_in[8];
  const float* w3  = (const float*)d_in[9];
  const float* g3  = (const float*)d_in[11];
  const float* b3  = (const float*)d_in[12];
  const float* wh1 = (const float*)d_in[13];
  const float* mh1 = (const float*)d_in[14];
  const float* G1  = (const float*)d_in[15];
  const float* wh2 = (const float*)d_in[16];
  const float* mh2 = (const float*)d_in[17];
  const float* G2  = (const float*)d_in[18];
  const float* fw  = (const float*)d_in[19];
  const float* fb  = (const float*)d_in[20];
  float* out = (float*)d_out;

  uint8_t* ws = (uint8_t*)d_ws;
  size_t off = 0;
  auto alloc = [&](size_t n) {
    uint8_t* p = ws + off;
    off += (n + 255) & ~(size_t)255;
    return p;
  };
  uint8_t* y1  = alloc((size_t)128 * LROWS * 128);   // fp8; later aliased as y3
  uint8_t* y2  = alloc((size_t)128 * LROWS * 256);   // fp8
  uint8_t* w2p = alloc((size_t)320 * 1024);
  uint8_t* w3p = alloc((size_t)192 * 1024);
  float* part1 = (float*)alloc((size_t)2176 * 256 * 4);
  float* part2 = (float*)alloc((size_t)5504 * 512 * 4);
  float* part3 = (float*)alloc((size_t)5504 * 256 * 4);
  float* s1 = (float*)alloc(128 * 4); float* t1 = (float*)alloc(128 * 4);
  float* s2 = (float*)alloc(256 * 4); float* t2 = (float*)alloc(256 * 4);
  float* s3 = (float*)alloc(128 * 4); float* t3 = (float*)alloc(128 * 4);
  float* fpart = (float*)alloc((size_t)8 * 128 * 128 * 4);
  float* W1n = (float*)alloc(128 * 128 * 4);
  float* W2n = (float*)alloc(16 * 128 * 4);
  uint8_t* y3 = y1;  // alias: y1 dead once conv2 done

  prepack_w2_kernel<<<640, 256, 0, stream>>>(w2, w2p);
  prepack_w3_kernel<<<384, 256, 0, stream>>>(w3, w3p);
  prep_nalu_kernel<<<72, 256, 0, stream>>>(wh1, mh1, wh2, mh2, W1n, W2n);

  conv1_kernel<<<dim3(17, 128), 256, 0, stream>>>(inp, w1, y1, part1);
  finalize_kernel<<<128, 256, 0, stream>>>(part1, 2176, 128, g1, b1, s1, t1);

  conv2_kernel<<<dim3(43, 2, 128), 256, 0, stream>>>(y1, w2p, s1, t1, y2, part2);
  finalize_kernel<<<256, 256, 0, stream>>>(part2, 5504, 256, g2, b2, s2, t2);

  conv3_kernel<<<dim3(43, 1, 128), 256, 0, stream>>>(y2, w3p, s2, t2, y3, part3);
  finalize_kernel<<<128, 256, 0, stream>>>(part3, 5504, 128, g3, b3, s3, t3);

  feat_kernel<<<dim3(8, 128), 256, 0, stream>>>(y3, s3, t3, fpart);
  head_kernel<<<128, 128, 0, stream>>>(fpart, W1n, G1, W2n, G2, fw, fb, out);
}